// Round 10
// baseline (181.313 us; speedup 1.0000x reference)
//
#include <hip/hip_runtime.h>
#include <hip/hip_fp16.h>
#include <math.h>

// GCN, N=50000 nodes, E=800000 edges, F_IN=128, H=128, C=16. f32 in/out; edges int32.
//
// R2-R21: CSR-by-dst pull, MFMA gemm1, fused gemm2, fp8 h1 gathers, pad-8 CSR,
// single-pass binning, bin||gemm1 one dispatch, per-edge dinv fma.
// R22/R23: 1-node/wave REGRESSED. R24: R21 l1 + pad-8 (160.3).
// R25: plane-split h1 (2x 3.2MB feature halves, L2-resident per XCD parity),
//      f32 h2acc atomic combine (158.9). R27: fp16 l2 + h2cvt, split-A dropped
//      (158.7, flat -> l2 was already L2-resident; bytes aren't the resource).
// R28 model: gather kernels sit at ~2.3-2.9 TB/s regardless of payload ->
//      RANDOM-REQUEST-COUNT bound. l1's hidden 2x: per-edge dinv[s] loads
//      (1.6M random 4B requests across both planes) equal the row-gather count.
// R28: pack dinv INTO colsrc: entry = src | fp16(dinv[src])<<16 (src<65536).
//      K1 bin also counts per-node deg (atomicAdd, hidden under gemm1 blocks);
//      K2 drops its count pass (reads deg[]) and packs w=rsqrtf(deg[src]+1)
//      while scattering. l1 gets src+weight from the colsrc word it already
//      streams -> zero per-edge random dinv requests. Dummies pack to N|0
//      (weight exactly 0). fp16 dinv error (5e-4) << fp8 quant (2^-6).

#define NBUCKET_SHIFT 8                   // bucket = dst >> 8 (256 nodes/bucket)
#define BIN_CHUNK 4096                    // edges per binning block
#define PAD_SLOP (7 << NBUCKET_SHIFT)     // per-bucket padded slack (1792)
#define CAP  5120                         // per-bucket pairs capacity (mean 4096, sd 64)
#define CCAP (CAP + PAD_SLOP)             // per-bucket padded colsrc capacity (6912)

typedef __bf16 bf16x8 __attribute__((ext_vector_type(8)));
typedef float  f32x4  __attribute__((ext_vector_type(4)));
typedef float  f32x2  __attribute__((ext_vector_type(2)));

__device__ __forceinline__ unsigned short pack_bf16(float f) {
    unsigned u = __float_as_uint(f);
    return (unsigned short)((u + 0x7fffu + ((u >> 16) & 1u)) >> 16);   // RNE
}

__device__ __forceinline__ float unpack_w(unsigned u) {
    return __half2float(__ushort_as_half((unsigned short)(u >> 16)));
}

// accumulate one 16 B chunk (16 fp8 features) scaled by w into 8 f32x2 regs
__device__ __forceinline__ void acc_fp8x16_fma(f32x2* a, uint4 v, float w) {
    f32x2 ww; ww.x = w; ww.y = w;
    a[0] += __builtin_amdgcn_cvt_pk_f32_fp8(v.x, false) * ww;
    a[1] += __builtin_amdgcn_cvt_pk_f32_fp8(v.x, true)  * ww;
    a[2] += __builtin_amdgcn_cvt_pk_f32_fp8(v.y, false) * ww;
    a[3] += __builtin_amdgcn_cvt_pk_f32_fp8(v.y, true)  * ww;
    a[4] += __builtin_amdgcn_cvt_pk_f32_fp8(v.z, false) * ww;
    a[5] += __builtin_amdgcn_cvt_pk_f32_fp8(v.z, true)  * ww;
    a[6] += __builtin_amdgcn_cvt_pk_f32_fp8(v.w, false) * ww;
    a[7] += __builtin_amdgcn_cvt_pk_f32_fp8(v.w, true)  * ww;
}

// accumulate one 16 B chunk (8 fp16 features) into 4 f32x2 regs
__device__ __forceinline__ void acc_fp16x8(f32x2* a, uint4 v) {
    float2 f;
    f = __half22float2(*(const __half2*)&v.x); a[0] += *(f32x2*)&f;
    f = __half22float2(*(const __half2*)&v.y); a[1] += *(f32x2*)&f;
    f = __half22float2(*(const __half2*)&v.z); a[2] += *(f32x2*)&f;
    f = __half22float2(*(const __half2*)&v.w); a[3] += *(f32x2*)&f;
}

// ---------------- K1: single-pass binning  ||  gemm1 MFMA (fused dispatch) ----
union K1Smem {
    struct { unsigned spair[BIN_CHUNK]; int lcnt[256]; int lbase[256]; } b; // 18 KB
    unsigned short wtp[16384];     // 32 KB  (gemm1 phase A)
    float outb[4][16 * 132];       // 33.8 KB (gemm1 phase B, reuses wtp space)
};

__global__ __launch_bounds__(256)
void bin_gemm1_kernel(const int* __restrict__ src, const int* __restrict__ dst,
                      int* __restrict__ bcur, unsigned* __restrict__ pairs,
                      int* __restrict__ deg, int E, int nbuckets, int nbins,
                      const float* __restrict__ x, const float* __restrict__ W1,
                      unsigned* __restrict__ h1b, int N) {
    __shared__ K1Smem sm;
    const int blk = blockIdx.x;
    const int tid = threadIdx.x;

    if (blk < nbins) {                // ---------------- bin path
        const int e0 = blk * BIN_CHUNK;
        const int cnt = min(BIN_CHUNK, E - e0);
        sm.b.lcnt[tid] = 0;
        __syncthreads();
        for (int i = tid; i < cnt; i += 256) {
            unsigned s = (unsigned)src[e0 + i], d = (unsigned)dst[e0 + i];
            sm.b.spair[i] = (d >> NBUCKET_SHIFT) << 24 | (d & 255u) << 16 | s;
            atomicAdd(&sm.b.lcnt[d >> NBUCKET_SHIFT], 1);
            atomicAdd(&deg[d], 1);    // per-node degree (L2 atomic, hidden)
        }
        __syncthreads();
        if (tid < nbuckets) {
            int c = sm.b.lcnt[tid];
            sm.b.lbase[tid] = (c > 0) ? atomicAdd(&bcur[tid], c) : 0;
            sm.b.lcnt[tid] = 0;       // reuse as local cursor
        }
        __syncthreads();
        for (int i = tid; i < cnt; i += 256) {
            unsigned p = sm.b.spair[i];
            int b = (int)(p >> 24);
            int off = atomicAdd(&sm.b.lcnt[b], 1);
            pairs[b * CAP + sm.b.lbase[b] + off] = p;
        }
        return;
    }

    // ---------------- gemm1 path
    const int gblk = blk - nbins;
    const int wave = tid >> 6, lane = tid & 63;
    const int q = lane >> 4, m = lane & 15;
    const int row0 = gblk * 64 + wave * 16;
    const int row = row0 + m;
    const int rowc = (row < N) ? row : (N - 1);   // clamp (OOB rows masked at store)

    // phase A: pack W1 -> LDS bf16 fragment layout (coalesced global reads)
    for (int it = tid; it < 16384; it += 256) {
        int k = it >> 7, n = it & 127;            // W1[k][n], row-major
        int t = n >> 4, mm = n & 15;
        int ks = k >> 5;
        int lane2 = (((k & 31) >> 3) << 4) | mm;
        int j = k & 7;
        sm.wtp[(t * 4 + ks) * 512 + lane2 * 8 + j] = pack_bf16(W1[it]);
    }
    __syncthreads();

    f32x4 acc[8];
#pragma unroll
    for (int t = 0; t < 8; t++) acc[t] = (f32x4)0.0f;

#pragma unroll
    for (int ks = 0; ks < 4; ks++) {
        const float4* xp = (const float4*)(x + (size_t)rowc * 128 + ks * 32 + q * 8);
        float4 f0 = xp[0], f1 = xp[1];
        float fv[8] = {f0.x, f0.y, f0.z, f0.w, f1.x, f1.y, f1.z, f1.w};
        bf16x8 ah;
#pragma unroll
        for (int j = 0; j < 8; j++) ah[j] = (__bf16)fv[j];
#pragma unroll
        for (int t = 0; t < 8; t++) {
            bf16x8 b = *(const bf16x8*)(sm.wtp + (size_t)(t * 4 + ks) * 512 + lane * 8);
            acc[t] = __builtin_amdgcn_mfma_f32_16x16x32_bf16(ah, b, acc[t], 0, 0, 0);
        }
    }
    __syncthreads();   // all waves done reading wtp before outb aliases it

#pragma unroll
    for (int t = 0; t < 8; t++)
#pragma unroll
        for (int r = 0; r < 4; r++)
            sm.outb[wave][(q * 4 + r) * 132 + t * 16 + m] = acc[t][r];
    __syncthreads();

    const int r2 = lane >> 2, j = lane & 3;
    const int orow = row0 + r2;
    if (orow < N) {
        const float* lrow = &sm.outb[wave][r2 * 132];
#pragma unroll
        for (int s = 0; s < 4; s++) {
            float4 a = *(const float4*)(lrow + s * 32 + j * 8);
            float4 b = *(const float4*)(lrow + s * 32 + j * 8 + 4);
            unsigned lo = __builtin_amdgcn_cvt_pk_fp8_f32(a.x, a.y, 0, false);
            lo = __builtin_amdgcn_cvt_pk_fp8_f32(a.z, a.w, lo, true);
            unsigned hi = __builtin_amdgcn_cvt_pk_fp8_f32(b.x, b.y, 0, false);
            hi = __builtin_amdgcn_cvt_pk_fp8_f32(b.z, b.w, hi, true);
            // feats s*32+j*8 ..+7; plane = s>>1, within-plane uint2 slot (s&1)*4+j
            ((uint2*)h1b)[((size_t)(s >> 1) * (N + 1) + orow) * 8 + (s & 1) * 4 + j]
                = make_uint2(lo, hi);
        }
    }
}

// ---------------- K2: per-bucket padded rowptr + dinv + packed colsrc --------
// deg[] precomputed by K1 -> no count pass. Scatter packs src | fp16(dinv[src])
// into colsrc. Dummy slots -> N | 0 (weight exactly 0; rows N also zeroed).
__global__ __launch_bounds__(256)
void bucket_build_kernel(const int* __restrict__ bcur, const unsigned* __restrict__ pairs,
                         const int* __restrict__ deg,
                         int* __restrict__ rowptr, int* __restrict__ rowcnt,
                         float* __restrict__ dinv, unsigned* __restrict__ colsrc,
                         unsigned* __restrict__ h1b, int N, int nbuckets) {
    __shared__ int cnt[256];
    __shared__ int sm[256];
    const int tid = threadIdx.x;
    const int blk = blockIdx.x;
    const int nb0 = blk << NBUCKET_SHIFT;

    if (blk == 0) {                   // zero the dummy rows (fresh each run)
        if (tid < 16) h1b[((size_t)0 * (N + 1) + N) * 16 + tid] = 0u;       // plane 0
        else if (tid < 32) h1b[((size_t)1 * (N + 1) + N) * 16 + (tid - 16)] = 0u; // plane 1
        else if (tid == 32) dinv[N] = 0.0f;   // h2cvt reads dinv[N]
        // h2acc row N zeroed by launch-side memset.
    }

    const int lo = blk * CAP;
    const int hi = lo + bcur[blk];

    int node = nb0 + tid;
    int v = (node < N) ? deg[node] : 0;   // real degree (from K1)
    int pdeg = (v + 7) & ~7;              // padded to x8
    sm[tid] = pdeg;
    __syncthreads();
#pragma unroll
    for (int off = 1; off < 256; off <<= 1) {
        int u = (tid >= off) ? sm[tid - off] : 0;
        __syncthreads();
        sm[tid] += u;
        __syncthreads();
    }
    int pexcl = sm[tid] - pdeg;
    const int start = blk * CCAP + pexcl;
    if (node < N) {
        rowptr[node] = start;
        rowcnt[node] = pdeg;
        dinv[node] = rsqrtf((float)v + 1.0f);   // +1 self-loop
    }
    __syncthreads();
    cnt[tid] = start;   // scatter cursor
    __syncthreads();
    for (int i = lo + tid; i < hi; i += 256) {
        unsigned p = pairs[i];
        unsigned s = p & 0xffffu;
        int pos = atomicAdd(&cnt[(int)(p >> 16) & 255], 1);
        float w = rsqrtf((float)deg[s] + 1.0f);
        unsigned w16 = (unsigned)__half_as_ushort(__float2half_rn(w));
        colsrc[pos] = s | (w16 << 16);
    }
    for (int p = start + v; p < start + pdeg; ++p)   // dummy fill (<=7/node)
        colsrc[p] = (unsigned)N;                      // weight bits = 0
}

// ---------------- K3: plane-split layer-1 pull + partial gemm2 ----------------
// Block 2b+p: node set b (16 nodes), feature plane p (64 feats, 64B rows).
// Lane = node n (bits 4-5) x edge-group g (bits 2-3) x 16B chunk c (bits 0-1).
// colsrc entries carry src (low 16) + fp16 dinv[src] (high 16): the gather
// loop issues ZERO per-edge random dinv loads. 16-edge batches, 4 gathers in
// flight, index prefetch; 4-edge sub-loop for the pad-8 remainder.
__global__ __launch_bounds__(256)
void l1_fused_kernel(const int* __restrict__ rowptr, const int* __restrict__ rowcnt,
                     const unsigned* __restrict__ colsrc,
                     const float* __restrict__ dinv, const unsigned* __restrict__ h1b,
                     const float* __restrict__ b1, const float* __restrict__ W2,
                     float* __restrict__ h2acc, int N) {
    __shared__ float rows[4][4][68];   // [wave][node][feat(+pad)], 4.25 KB
    __shared__ float w2s[64 * 16];     // plane's W2 half [k][col], 4 KB
    const int tid = threadIdx.x;
    const int wave = tid >> 6, lane = tid & 63;
    const int c = lane & 3;            // 16B chunk 0..3 (plane feats c*16..+15)
    const int g = (lane >> 2) & 3;     // edge group 0..3
    const int n = lane >> 4;           // node 0..3 within wave
    const int p = blockIdx.x & 1;      // feature plane
    const int d = (blockIdx.x >> 1) * 16 + wave * 4 + n;

    for (int i = tid; i < 256; i += 256)          // 64x16 floats = 256 float4
        ((float4*)w2s)[i] = ((const float4*)W2)[p * 256 + i];

    const uint4* hq = (const uint4*)h1b + (size_t)p * (N + 1) * 4;  // row = 4 uint4

    if (d < N) {
        const float dvd = dinv[d];
        f32x2 a[8];
#pragma unroll
        for (int j = 0; j < 8; j++) a[j] = (f32x2)0.0f;

        if (g == 0)                   // self-loop term: h1[d] * dinv[d]
            acc_fp8x16_fma(a, hq[(size_t)d * 4 + c], dvd);

        int i = rowptr[d];
        const int end = i + rowcnt[d];     // multiple of 8
        unsigned u0 = 0, u1 = 0, u2 = 0, u3 = 0;
        if (i + 16 <= end) {
            u0 = colsrc[i + g];      u1 = colsrc[i + g + 4];
            u2 = colsrc[i + g + 8];  u3 = colsrc[i + g + 12];
        }
        while (i + 16 <= end) {
            uint4 v0 = hq[(size_t)(u0 & 0xffffu) * 4 + c];
            uint4 v1 = hq[(size_t)(u1 & 0xffffu) * 4 + c];
            uint4 v2 = hq[(size_t)(u2 & 0xffffu) * 4 + c];
            uint4 v3 = hq[(size_t)(u3 & 0xffffu) * 4 + c];
            float w0 = unpack_w(u0), w1 = unpack_w(u1);
            float w2 = unpack_w(u2), w3 = unpack_w(u3);
            i += 16;
            if (i + 16 <= end) {          // prefetch next batch's entries
                u0 = colsrc[i + g];      u1 = colsrc[i + g + 4];
                u2 = colsrc[i + g + 8];  u3 = colsrc[i + g + 12];
            }
            acc_fp8x16_fma(a, v0, w0); acc_fp8x16_fma(a, v1, w1);
            acc_fp8x16_fma(a, v2, w2); acc_fp8x16_fma(a, v3, w3);
        }
        for (; i + 4 <= end; i += 4) {    // 8-edge pad remainder (0 or 2 iters)
            unsigned ux = colsrc[i + g];
            acc_fp8x16_fma(a, hq[(size_t)(ux & 0xffffu) * 4 + c], unpack_w(ux));
        }

#pragma unroll
        for (int j = 0; j < 8; j++) { // combine the 4 edge groups (bits 2-3)
            a[j].x += __shfl_xor(a[j].x, 4, 64);
            a[j].y += __shfl_xor(a[j].y, 4, 64);
            a[j].x += __shfl_xor(a[j].x, 8, 64);
            a[j].y += __shfl_xor(a[j].y, 8, 64);
        }

        if (g == 0) {                 // relu(dinv*agg + b1-half) -> LDS row
            float* rbase = &rows[wave][n][c * 16];
#pragma unroll
            for (int t = 0; t < 4; t++) {
                float4 bb = ((const float4*)b1)[p * 16 + c * 4 + t];
                float4 o;
                o.x = fmaxf(a[2 * t].x * dvd + bb.x, 0.0f);
                o.y = fmaxf(a[2 * t].y * dvd + bb.y, 0.0f);
                o.z = fmaxf(a[2 * t + 1].x * dvd + bb.z, 0.0f);
                o.w = fmaxf(a[2 * t + 1].y * dvd + bb.w, 0.0f);
                *(float4*)(rbase + 4 * t) = o;
            }
        }
    }
    __syncthreads();

    // partial gemm2: lane = node n2 (bits 4-5) x col (bits 0-3); 64-k dot.
    const int n2 = lane >> 4, col = lane & 15;
    const int d2 = (blockIdx.x >> 1) * 16 + wave * 4 + n2;
    if (d2 < N) {
        const float* r = &rows[wave][n2][0];
        float p0 = 0.0f, p1 = 0.0f;
#pragma unroll
        for (int k = 0; k < 32; k++) {       // 2-way ILP
            p0 = fmaf(r[k],      w2s[k * 16 + col],        p0);
            p1 = fmaf(r[k + 32], w2s[(k + 32) * 16 + col], p1);
        }
        atomicAdd(&h2acc[(size_t)d2 * 16 + col], p0 + p1);
    }
}

// ---------------- K3b: h2 convert  h2h[s] = fp16(h2acc[s] * dinv[s]) ---------
__global__ __launch_bounds__(256)
void h2cvt_kernel(const float* __restrict__ h2acc, const float* __restrict__ dinv,
                  unsigned* __restrict__ h2h, int N) {
    int idx = blockIdx.x * 256 + threadIdx.x;   // one float4 = quarter row
    if (idx >= (N + 1) * 4) return;
    float dv = dinv[idx >> 2];
    float4 v = ((const float4*)h2acc)[idx];
    __half2 lo = __floats2half2_rn(v.x * dv, v.y * dv);
    __half2 hi = __floats2half2_rn(v.z * dv, v.w * dv);
    ((uint2*)h2h)[idx] = make_uint2(*(unsigned*)&lo, *(unsigned*)&hi);
}

// ---------------- K4: fused layer-2 pull + log_softmax (fp16 gathers) ---------
// Lane = node n (bits 4-5) x edge-group g (bits 1-3) x 16B chunk c (bit 0).
// Batch = 8 edges/node (pad-8); 2-deep gather pipeline. Rows PRESCALED by
// dinv[s]; colsrc entry low 16 bits = src.
__global__ __launch_bounds__(256)
void l2_kernel(const int* __restrict__ rowptr, const int* __restrict__ rowcnt,
               const unsigned* __restrict__ colsrc,
               const float* __restrict__ dinv, const unsigned* __restrict__ h2s,
               const float* __restrict__ b2, float* __restrict__ out, int N) {
    const int tid = threadIdx.x;
    const int wave = tid >> 6, lane = tid & 63;
    const int n = lane >> 4;          // node 0..3 within wave
    const int g = (lane >> 1) & 7;    // edge group 0..7
    const int c = lane & 1;           // 16B chunk (8 fp16 feats, c*8..c*8+7)
    const int d = blockIdx.x * 16 + wave * 4 + n;
    if (d >= N) return;
    const uint4* h2q = (const uint4*)h2s;   // node row = 2 uint4 (32 B)

    f32x2 a[4];
#pragma unroll
    for (int j = 0; j < 4; j++) a[j] = (f32x2)0.0f;

    if (g == 0)                        // self-loop term (prescaled by dinv[d])
        acc_fp16x8(a, h2q[(size_t)d * 2 + c]);

    int i = rowptr[d];
    const int end = i + rowcnt[d];     // multiple of 8
    uint4 v; unsigned u2 = 0;
    if (i < end) {
        unsigned u = colsrc[i + g];
        v = h2q[(size_t)(u & 0xffffu) * 2 + c];
    }
    if (i + 8 < end) u2 = colsrc[i + 8 + g];
    while (i < end) {
        uint4 vc = v;
        if (i + 8 < end) v = h2q[(size_t)(u2 & 0xffffu) * 2 + c];
        if (i + 16 < end) u2 = colsrc[i + 16 + g];
        i += 8;
        acc_fp16x8(a, vc);
    }

#pragma unroll
    for (int j = 0; j < 4; j++) {      // combine the 8 edge groups (bits 1-3)
#pragma unroll
        for (int off = 2; off <= 8; off <<= 1) {
            a[j].x += __shfl_xor(a[j].x, off, 64);
            a[j].y += __shfl_xor(a[j].y, off, 64);
        }
    }

    const float dv = dinv[d];
    const float* af = (const float*)a;     // feats c*8 .. c*8+7
    float v8[8];
#pragma unroll
    for (int j = 0; j < 8; j++) v8[j] = af[j] * dv + b2[c * 8 + j];

    float m = v8[0];
#pragma unroll
    for (int j = 1; j < 8; j++) m = fmaxf(m, v8[j]);
    m = fmaxf(m, __shfl_xor(m, 1, 64));    // combine c-halves
    float e = 0.0f;
#pragma unroll
    for (int j = 0; j < 8; j++) e += expf(v8[j] - m);
    e += __shfl_xor(e, 1, 64);
    float lse = m + logf(e);

    if (g == 0) {
        float4 o0 = make_float4(v8[0] - lse, v8[1] - lse, v8[2] - lse, v8[3] - lse);
        float4 o1 = make_float4(v8[4] - lse, v8[5] - lse, v8[6] - lse, v8[7] - lse);
        float4* op = (float4*)(out + (size_t)d * 16 + c * 8);
        op[0] = o0; op[1] = o1;
    }
}

extern "C" void kernel_launch(void* const* d_in, const int* in_sizes, int n_in,
                              void* d_out, int out_size, void* d_ws, size_t ws_size,
                              hipStream_t stream) {
    const float* x  = (const float*)d_in[0];
    const int*  ei  = (const int*)d_in[1];
    const float* W1 = (const float*)d_in[2];
    const float* b1 = (const float*)d_in[3];
    const float* W2 = (const float*)d_in[4];
    const float* b2 = (const float*)d_in[5];
    float* out = (float*)d_out;

    const int N = in_sizes[0] / 128;   // 50000 (< 65536 required for uint packing)
    const int E = in_sizes[1] / 2;     // 800000
    const int* src = ei;
    const int* dst = ei + E;
    const int nbuckets = (N + 255) >> NBUCKET_SHIFT;   // 196 (< 256 required)
    const int nbins = (E + BIN_CHUNK - 1) / BIN_CHUNK; // 196
    const int g1blocks = (N + 63) / 64;                // 782 gemm1 blocks

    // Workspace layout (4B units):
    //   dinv    : N+16 floats (dinv[N] = 0)
    //   rowptr  : N ints (padded starts)
    //   rowcnt  : N ints (padded degrees, x8)
    //   bcur    : 256 ints   \
    //   deg     : N+16 ints   | single contiguous memset region
    //   h2acc   : (N+1)*16 f32/
    //   colsrc  : nbuckets*CCAP uints (5.4 MB, packed src|fp16(dinv))
    //   pairs   : nbuckets*CAP uints (4.0 MB; dead after K2 -> h2h overlays)
    //   h1b     : 2 planes x (N+1)*16 uints (6.4 MB; 64B fp8 rows; row N = 0)
    float*          wsf     = (float*)d_ws;
    float*          dinv    = wsf;
    int*            rowptr  = (int*)(wsf + N + 16);
    int*            rowcnt  = rowptr + N;
    int*            bcur    = rowcnt + N;
    int*            deg     = bcur + 256;
    float*          h2acc   = (float*)(deg + N + 16);
    unsigned*       colsrc  = (unsigned*)(h2acc + (size_t)(N + 1) * 16);
    unsigned*       pairs   = colsrc + (size_t)nbuckets * CCAP;
    unsigned*       h1b     = pairs + (size_t)nbuckets * CAP;
    unsigned*       h2h     = pairs;   // overlays dead pairs (1.6 MB of 4.0 MB)

    const size_t zero_ints = 256 + (size_t)(N + 16) + (size_t)(N + 1) * 16;

    // ---- K1: bin (blocks [0,nbins)) || gemm1 (blocks [nbins,nbins+g1blocks)) ----
    hipMemsetAsync(bcur, 0, zero_ints * sizeof(int), stream);
    bin_gemm1_kernel<<<nbins + g1blocks, 256, 0, stream>>>(src, dst, bcur, pairs,
                                                           deg, E, nbuckets, nbins,
                                                           x, W1, h1b, N);

    // ---- K2: CSR build (rowptr/rowcnt/dinv/packed colsrc) ----
    bucket_build_kernel<<<nbuckets, 256, 0, stream>>>(bcur, pairs, deg, rowptr,
                                                      rowcnt, dinv, colsrc, h1b,
                                                      N, nbuckets);

    // ---- K3: plane-split layer-1 pull + partial gemm2 (f32 atomics) ----
    l1_fused_kernel<<<((N + 15) / 16) * 2, 256, 0, stream>>>(rowptr, rowcnt, colsrc,
                                                             dinv, h1b, b1, W2,
                                                             h2acc, N);

    // ---- K3b: h2h = fp16(h2acc * dinv)  (prescaled 32 B rows for l2) ----
    h2cvt_kernel<<<((N + 1) * 4 + 255) / 256, 256, 0, stream>>>(h2acc, dinv, h2h, N);

    // ---- K4: fused pull-aggregation 2 + bias + log_softmax ----
    l2_kernel<<<(N + 15) / 16, 256, 0, stream>>>(rowptr, rowcnt, colsrc, dinv, h2h,
                                                 b2, out, N);
}

// Round 11
// 165.281 us; speedup vs baseline: 1.0970x; 1.0970x over previous
//
#include <hip/hip_runtime.h>
#include <hip/hip_fp16.h>
#include <math.h>

// GCN, N=50000 nodes, E=800000 edges, F_IN=128, H=128, C=16. f32 in/out; edges int32.
//
// R2-R21: CSR-by-dst pull, MFMA gemm1, fused gemm2, fp8 h1 gathers, pad-8 CSR,
// single-pass binning, bin||gemm1 one dispatch, per-edge dinv fma.
// R24: R21 l1 + pad-8 (160.3). R25: plane-split h1 (2x 3.2MB, per-XCD L2) +
// f32 h2acc atomics (158.9). R27: fp16 l2 via h2cvt, split-A dropped (158.7).
// R28: packed colsrc (src|fp16(dinv)<<16) REGRESSED to 181.3 -- NOT the packing:
//      the 800K random deg atomicAdds in K1's bin path (+20us, counter-proven:
//      bin_gemm1 51us, WRITE 35MB). l1's delta was never measured.
// R29: same packed-colsrc l1/l2, atomics-free setup: K1 = exact R27 bin path;
//      K2 = R27 count-pass + writes fp16 dinv16[] table (100KB) + ptot[];
//      new K2b streaming pack kernel (colsrc[i] |= dinv16[src]<<16, in-place,
//      ~4us). Isolates the request-count hypothesis: vs R27 the only l1-side
//      change is zero per-edge random dinv loads (was 1.6M across 2 planes).

#define NBUCKET_SHIFT 8                   // bucket = dst >> 8 (256 nodes/bucket)
#define BIN_CHUNK 4096                    // edges per binning block
#define PAD_SLOP (7 << NBUCKET_SHIFT)     // per-bucket padded slack (1792)
#define CAP  5120                         // per-bucket pairs capacity (mean 4096, sd 64)
#define CCAP (CAP + PAD_SLOP)             // per-bucket padded colsrc capacity (6912)
#define PSTRIPES 8                        // K2b blocks per bucket

typedef __bf16 bf16x8 __attribute__((ext_vector_type(8)));
typedef float  f32x4  __attribute__((ext_vector_type(4)));
typedef float  f32x2  __attribute__((ext_vector_type(2)));

__device__ __forceinline__ unsigned short pack_bf16(float f) {
    unsigned u = __float_as_uint(f);
    return (unsigned short)((u + 0x7fffu + ((u >> 16) & 1u)) >> 16);   // RNE
}

__device__ __forceinline__ float unpack_w(unsigned u) {
    return __half2float(__ushort_as_half((unsigned short)(u >> 16)));
}

// accumulate one 16 B chunk (16 fp8 features) scaled by w into 8 f32x2 regs
__device__ __forceinline__ void acc_fp8x16_fma(f32x2* a, uint4 v, float w) {
    f32x2 ww; ww.x = w; ww.y = w;
    a[0] += __builtin_amdgcn_cvt_pk_f32_fp8(v.x, false) * ww;
    a[1] += __builtin_amdgcn_cvt_pk_f32_fp8(v.x, true)  * ww;
    a[2] += __builtin_amdgcn_cvt_pk_f32_fp8(v.y, false) * ww;
    a[3] += __builtin_amdgcn_cvt_pk_f32_fp8(v.y, true)  * ww;
    a[4] += __builtin_amdgcn_cvt_pk_f32_fp8(v.z, false) * ww;
    a[5] += __builtin_amdgcn_cvt_pk_f32_fp8(v.z, true)  * ww;
    a[6] += __builtin_amdgcn_cvt_pk_f32_fp8(v.w, false) * ww;
    a[7] += __builtin_amdgcn_cvt_pk_f32_fp8(v.w, true)  * ww;
}

// accumulate one 16 B chunk (8 fp16 features) into 4 f32x2 regs
__device__ __forceinline__ void acc_fp16x8(f32x2* a, uint4 v) {
    float2 f;
    f = __half22float2(*(const __half2*)&v.x); a[0] += *(f32x2*)&f;
    f = __half22float2(*(const __half2*)&v.y); a[1] += *(f32x2*)&f;
    f = __half22float2(*(const __half2*)&v.z); a[2] += *(f32x2*)&f;
    f = __half22float2(*(const __half2*)&v.w); a[3] += *(f32x2*)&f;
}

// ---------------- K1: single-pass binning  ||  gemm1 MFMA (fused dispatch) ----
union K1Smem {
    struct { unsigned spair[BIN_CHUNK]; int lcnt[256]; int lbase[256]; } b; // 18 KB
    unsigned short wtp[16384];     // 32 KB  (gemm1 phase A)
    float outb[4][16 * 132];       // 33.8 KB (gemm1 phase B, reuses wtp space)
};

__global__ __launch_bounds__(256)
void bin_gemm1_kernel(const int* __restrict__ src, const int* __restrict__ dst,
                      int* __restrict__ bcur, unsigned* __restrict__ pairs,
                      int E, int nbuckets, int nbins,
                      const float* __restrict__ x, const float* __restrict__ W1,
                      unsigned* __restrict__ h1b, int N) {
    __shared__ K1Smem sm;
    const int blk = blockIdx.x;
    const int tid = threadIdx.x;

    if (blk < nbins) {                // ---------------- bin path (R27, no atomics)
        const int e0 = blk * BIN_CHUNK;
        const int cnt = min(BIN_CHUNK, E - e0);
        sm.b.lcnt[tid] = 0;
        __syncthreads();
        for (int i = tid; i < cnt; i += 256) {
            unsigned s = (unsigned)src[e0 + i], d = (unsigned)dst[e0 + i];
            sm.b.spair[i] = (d >> NBUCKET_SHIFT) << 24 | (d & 255u) << 16 | s;
            atomicAdd(&sm.b.lcnt[d >> NBUCKET_SHIFT], 1);
        }
        __syncthreads();
        if (tid < nbuckets) {
            int c = sm.b.lcnt[tid];
            sm.b.lbase[tid] = (c > 0) ? atomicAdd(&bcur[tid], c) : 0;
            sm.b.lcnt[tid] = 0;       // reuse as local cursor
        }
        __syncthreads();
        for (int i = tid; i < cnt; i += 256) {
            unsigned p = sm.b.spair[i];
            int b = (int)(p >> 24);
            int off = atomicAdd(&sm.b.lcnt[b], 1);
            pairs[b * CAP + sm.b.lbase[b] + off] = p;
        }
        return;
    }

    // ---------------- gemm1 path
    const int gblk = blk - nbins;
    const int wave = tid >> 6, lane = tid & 63;
    const int q = lane >> 4, m = lane & 15;
    const int row0 = gblk * 64 + wave * 16;
    const int row = row0 + m;
    const int rowc = (row < N) ? row : (N - 1);   // clamp (OOB rows masked at store)

    // phase A: pack W1 -> LDS bf16 fragment layout (coalesced global reads)
    for (int it = tid; it < 16384; it += 256) {
        int k = it >> 7, n = it & 127;            // W1[k][n], row-major
        int t = n >> 4, mm = n & 15;
        int ks = k >> 5;
        int lane2 = (((k & 31) >> 3) << 4) | mm;
        int j = k & 7;
        sm.wtp[(t * 4 + ks) * 512 + lane2 * 8 + j] = pack_bf16(W1[it]);
    }
    __syncthreads();

    f32x4 acc[8];
#pragma unroll
    for (int t = 0; t < 8; t++) acc[t] = (f32x4)0.0f;

#pragma unroll
    for (int ks = 0; ks < 4; ks++) {
        const float4* xp = (const float4*)(x + (size_t)rowc * 128 + ks * 32 + q * 8);
        float4 f0 = xp[0], f1 = xp[1];
        float fv[8] = {f0.x, f0.y, f0.z, f0.w, f1.x, f1.y, f1.z, f1.w};
        bf16x8 ah;
#pragma unroll
        for (int j = 0; j < 8; j++) ah[j] = (__bf16)fv[j];
#pragma unroll
        for (int t = 0; t < 8; t++) {
            bf16x8 b = *(const bf16x8*)(sm.wtp + (size_t)(t * 4 + ks) * 512 + lane * 8);
            acc[t] = __builtin_amdgcn_mfma_f32_16x16x32_bf16(ah, b, acc[t], 0, 0, 0);
        }
    }
    __syncthreads();   // all waves done reading wtp before outb aliases it

#pragma unroll
    for (int t = 0; t < 8; t++)
#pragma unroll
        for (int r = 0; r < 4; r++)
            sm.outb[wave][(q * 4 + r) * 132 + t * 16 + m] = acc[t][r];
    __syncthreads();

    const int r2 = lane >> 2, j = lane & 3;
    const int orow = row0 + r2;
    if (orow < N) {
        const float* lrow = &sm.outb[wave][r2 * 132];
#pragma unroll
        for (int s = 0; s < 4; s++) {
            float4 a = *(const float4*)(lrow + s * 32 + j * 8);
            float4 b = *(const float4*)(lrow + s * 32 + j * 8 + 4);
            unsigned lo = __builtin_amdgcn_cvt_pk_fp8_f32(a.x, a.y, 0, false);
            lo = __builtin_amdgcn_cvt_pk_fp8_f32(a.z, a.w, lo, true);
            unsigned hi = __builtin_amdgcn_cvt_pk_fp8_f32(b.x, b.y, 0, false);
            hi = __builtin_amdgcn_cvt_pk_fp8_f32(b.z, b.w, hi, true);
            // feats s*32+j*8 ..+7; plane = s>>1, within-plane uint2 slot (s&1)*4+j
            ((uint2*)h1b)[((size_t)(s >> 1) * (N + 1) + orow) * 8 + (s & 1) * 4 + j]
                = make_uint2(lo, hi);
        }
    }
}

// ---------------- K2: per-bucket padded rowptr + dinv/dinv16 + colsrc --------
// R27 count-pass restored (LDS atomics over this bucket's pairs). Also writes
// the fp16 dinv16[] table and ptot[bucket] (padded total) for the K2b packer.
// Dummy slots -> N (dinv16[N] = 0 -> packed weight exactly 0).
__global__ __launch_bounds__(256)
void bucket_build_kernel(const int* __restrict__ bcur, const unsigned* __restrict__ pairs,
                         int* __restrict__ rowptr, int* __restrict__ rowcnt,
                         float* __restrict__ dinv, unsigned short* __restrict__ dinv16,
                         int* __restrict__ ptot, unsigned* __restrict__ colsrc,
                         unsigned* __restrict__ h1b, int N, int nbuckets) {
    __shared__ int cnt[256];
    __shared__ int sm[256];
    const int tid = threadIdx.x;
    const int blk = blockIdx.x;
    const int nb0 = blk << NBUCKET_SHIFT;

    if (blk == 0) {                   // zero the dummy rows (fresh each run)
        if (tid < 16) h1b[((size_t)0 * (N + 1) + N) * 16 + tid] = 0u;       // plane 0
        else if (tid < 32) h1b[((size_t)1 * (N + 1) + N) * 16 + (tid - 16)] = 0u; // plane 1
        else if (tid == 32) { dinv[N] = 0.0f; dinv16[N] = 0; }
        // h2acc row N zeroed by launch-side memset.
    }

    const int lo = blk * CAP;
    const int hi = lo + bcur[blk];
    cnt[tid] = 0;
    __syncthreads();

    for (int i = lo + tid; i < hi; i += 256)
        atomicAdd(&cnt[(int)(pairs[i] >> 16) & 255], 1);
    __syncthreads();

    int v = cnt[tid];                  // real degree of this node
    int pdeg = (v + 7) & ~7;           // padded to x8
    sm[tid] = pdeg;
    __syncthreads();
#pragma unroll
    for (int off = 1; off < 256; off <<= 1) {
        int u = (tid >= off) ? sm[tid - off] : 0;
        __syncthreads();
        sm[tid] += u;
        __syncthreads();
    }
    int pexcl = sm[tid] - pdeg;
    const int start = blk * CCAP + pexcl;
    int node = nb0 + tid;
    if (node < N) {
        rowptr[node] = start;
        rowcnt[node] = pdeg;
        float w = rsqrtf((float)v + 1.0f);   // +1 self-loop
        dinv[node] = w;
        dinv16[node] = __half_as_ushort(__float2half_rn(w));
    }
    if (tid == 255) ptot[blk] = sm[255];     // padded total for K2b
    __syncthreads();
    cnt[tid] = start;   // reuse as scatter cursor
    __syncthreads();
    for (int i = lo + tid; i < hi; i += 256) {
        unsigned p = pairs[i];
        int pos = atomicAdd(&cnt[(int)(p >> 16) & 255], 1);
        colsrc[pos] = p & 0xffffu;           // plain src; K2b packs weight
    }
    for (int p = start + v; p < start + pdeg; ++p)   // dummy fill (<=7/node)
        colsrc[p] = (unsigned)N;
}

// ---------------- K2b: pack fp16 weight into colsrc (streaming, in-place) ----
// colsrc[i] = src | dinv16[src] << 16. Random reads hit the 100 KB L2-hot
// table; moves the per-edge dinv lookups OUT of l1's critical gather loop
// (where they ran twice -- once per plane).
__global__ __launch_bounds__(256)
void pack_kernel(const int* __restrict__ ptot, const unsigned short* __restrict__ dinv16,
                 unsigned* __restrict__ colsrc, int nbuckets) {
    const int bkt = blockIdx.x / PSTRIPES;
    const int st  = blockIdx.x % PSTRIPES;
    const int tot = ptot[bkt];
    const size_t base = (size_t)bkt * CCAP;
    for (int i = st * 256 + threadIdx.x; i < tot; i += 256 * PSTRIPES) {
        unsigned u = colsrc[base + i];
        colsrc[base + i] = u | ((unsigned)dinv16[u] << 16);
    }
}

// ---------------- K3: plane-split layer-1 pull + partial gemm2 ----------------
// Block 2b+p: node set b (16 nodes), feature plane p (64 feats, 64B rows).
// Lane = node n (bits 4-5) x edge-group g (bits 2-3) x 16B chunk c (bits 0-1).
// colsrc entries carry src (low 16) + fp16 dinv[src] (high 16): ZERO per-edge
// random dinv loads. 16-edge batches, 4 gathers in flight, index prefetch.
__global__ __launch_bounds__(256)
void l1_fused_kernel(const int* __restrict__ rowptr, const int* __restrict__ rowcnt,
                     const unsigned* __restrict__ colsrc,
                     const float* __restrict__ dinv, const unsigned* __restrict__ h1b,
                     const float* __restrict__ b1, const float* __restrict__ W2,
                     float* __restrict__ h2acc, int N) {
    __shared__ float rows[4][4][68];   // [wave][node][feat(+pad)], 4.25 KB
    __shared__ float w2s[64 * 16];     // plane's W2 half [k][col], 4 KB
    const int tid = threadIdx.x;
    const int wave = tid >> 6, lane = tid & 63;
    const int c = lane & 3;            // 16B chunk 0..3 (plane feats c*16..+15)
    const int g = (lane >> 2) & 3;     // edge group 0..3
    const int n = lane >> 4;           // node 0..3 within wave
    const int p = blockIdx.x & 1;      // feature plane
    const int d = (blockIdx.x >> 1) * 16 + wave * 4 + n;

    for (int i = tid; i < 256; i += 256)          // 64x16 floats = 256 float4
        ((float4*)w2s)[i] = ((const float4*)W2)[p * 256 + i];

    const uint4* hq = (const uint4*)h1b + (size_t)p * (N + 1) * 4;  // row = 4 uint4

    if (d < N) {
        const float dvd = dinv[d];
        f32x2 a[8];
#pragma unroll
        for (int j = 0; j < 8; j++) a[j] = (f32x2)0.0f;

        if (g == 0)                   // self-loop term: h1[d] * dinv[d]
            acc_fp8x16_fma(a, hq[(size_t)d * 4 + c], dvd);

        int i = rowptr[d];
        const int end = i + rowcnt[d];     // multiple of 8
        unsigned u0 = 0, u1 = 0, u2 = 0, u3 = 0;
        if (i + 16 <= end) {
            u0 = colsrc[i + g];      u1 = colsrc[i + g + 4];
            u2 = colsrc[i + g + 8];  u3 = colsrc[i + g + 12];
        }
        while (i + 16 <= end) {
            uint4 v0 = hq[(size_t)(u0 & 0xffffu) * 4 + c];
            uint4 v1 = hq[(size_t)(u1 & 0xffffu) * 4 + c];
            uint4 v2 = hq[(size_t)(u2 & 0xffffu) * 4 + c];
            uint4 v3 = hq[(size_t)(u3 & 0xffffu) * 4 + c];
            float w0 = unpack_w(u0), w1 = unpack_w(u1);
            float w2 = unpack_w(u2), w3 = unpack_w(u3);
            i += 16;
            if (i + 16 <= end) {          // prefetch next batch's entries
                u0 = colsrc[i + g];      u1 = colsrc[i + g + 4];
                u2 = colsrc[i + g + 8];  u3 = colsrc[i + g + 12];
            }
            acc_fp8x16_fma(a, v0, w0); acc_fp8x16_fma(a, v1, w1);
            acc_fp8x16_fma(a, v2, w2); acc_fp8x16_fma(a, v3, w3);
        }
        for (; i + 4 <= end; i += 4) {    // 8-edge pad remainder (0 or 2 iters)
            unsigned ux = colsrc[i + g];
            acc_fp8x16_fma(a, hq[(size_t)(ux & 0xffffu) * 4 + c], unpack_w(ux));
        }

#pragma unroll
        for (int j = 0; j < 8; j++) { // combine the 4 edge groups (bits 2-3)
            a[j].x += __shfl_xor(a[j].x, 4, 64);
            a[j].y += __shfl_xor(a[j].y, 4, 64);
            a[j].x += __shfl_xor(a[j].x, 8, 64);
            a[j].y += __shfl_xor(a[j].y, 8, 64);
        }

        if (g == 0) {                 // relu(dinv*agg + b1-half) -> LDS row
            float* rbase = &rows[wave][n][c * 16];
#pragma unroll
            for (int t = 0; t < 4; t++) {
                float4 bb = ((const float4*)b1)[p * 16 + c * 4 + t];
                float4 o;
                o.x = fmaxf(a[2 * t].x * dvd + bb.x, 0.0f);
                o.y = fmaxf(a[2 * t].y * dvd + bb.y, 0.0f);
                o.z = fmaxf(a[2 * t + 1].x * dvd + bb.z, 0.0f);
                o.w = fmaxf(a[2 * t + 1].y * dvd + bb.w, 0.0f);
                *(float4*)(rbase + 4 * t) = o;
            }
        }
    }
    __syncthreads();

    // partial gemm2: lane = node n2 (bits 4-5) x col (bits 0-3); 64-k dot.
    const int n2 = lane >> 4, col = lane & 15;
    const int d2 = (blockIdx.x >> 1) * 16 + wave * 4 + n2;
    if (d2 < N) {
        const float* r = &rows[wave][n2][0];
        float p0 = 0.0f, p1 = 0.0f;
#pragma unroll
        for (int k = 0; k < 32; k++) {       // 2-way ILP
            p0 = fmaf(r[k],      w2s[k * 16 + col],        p0);
            p1 = fmaf(r[k + 32], w2s[(k + 32) * 16 + col], p1);
        }
        atomicAdd(&h2acc[(size_t)d2 * 16 + col], p0 + p1);
    }
}

// ---------------- K3b: h2 convert  h2h[s] = fp16(h2acc[s] * dinv[s]) ---------
__global__ __launch_bounds__(256)
void h2cvt_kernel(const float* __restrict__ h2acc, const float* __restrict__ dinv,
                  unsigned* __restrict__ h2h, int N) {
    int idx = blockIdx.x * 256 + threadIdx.x;   // one float4 = quarter row
    if (idx >= (N + 1) * 4) return;
    float dv = dinv[idx >> 2];
    float4 v = ((const float4*)h2acc)[idx];
    __half2 lo = __floats2half2_rn(v.x * dv, v.y * dv);
    __half2 hi = __floats2half2_rn(v.z * dv, v.w * dv);
    ((uint2*)h2h)[idx] = make_uint2(*(unsigned*)&lo, *(unsigned*)&hi);
}

// ---------------- K4: fused layer-2 pull + log_softmax (fp16 gathers) ---------
// Lane = node n (bits 4-5) x edge-group g (bits 1-3) x 16B chunk c (bit 0).
// Batch = 8 edges/node (pad-8); 2-deep gather pipeline. Rows PRESCALED by
// dinv[s]; colsrc entry low 16 bits = src.
__global__ __launch_bounds__(256)
void l2_kernel(const int* __restrict__ rowptr, const int* __restrict__ rowcnt,
               const unsigned* __restrict__ colsrc,
               const float* __restrict__ dinv, const unsigned* __restrict__ h2s,
               const float* __restrict__ b2, float* __restrict__ out, int N) {
    const int tid = threadIdx.x;
    const int wave = tid >> 6, lane = tid & 63;
    const int n = lane >> 4;          // node 0..3 within wave
    const int g = (lane >> 1) & 7;    // edge group 0..7
    const int c = lane & 1;           // 16B chunk (8 fp16 feats, c*8..c*8+7)
    const int d = blockIdx.x * 16 + wave * 4 + n;
    if (d >= N) return;
    const uint4* h2q = (const uint4*)h2s;   // node row = 2 uint4 (32 B)

    f32x2 a[4];
#pragma unroll
    for (int j = 0; j < 4; j++) a[j] = (f32x2)0.0f;

    if (g == 0)                        // self-loop term (prescaled by dinv[d])
        acc_fp16x8(a, h2q[(size_t)d * 2 + c]);

    int i = rowptr[d];
    const int end = i + rowcnt[d];     // multiple of 8
    uint4 v; unsigned u2 = 0;
    if (i < end) {
        unsigned u = colsrc[i + g];
        v = h2q[(size_t)(u & 0xffffu) * 2 + c];
    }
    if (i + 8 < end) u2 = colsrc[i + 8 + g];
    while (i < end) {
        uint4 vc = v;
        if (i + 8 < end) v = h2q[(size_t)(u2 & 0xffffu) * 2 + c];
        if (i + 16 < end) u2 = colsrc[i + 16 + g];
        i += 8;
        acc_fp16x8(a, vc);
    }

#pragma unroll
    for (int j = 0; j < 4; j++) {      // combine the 8 edge groups (bits 1-3)
#pragma unroll
        for (int off = 2; off <= 8; off <<= 1) {
            a[j].x += __shfl_xor(a[j].x, off, 64);
            a[j].y += __shfl_xor(a[j].y, off, 64);
        }
    }

    const float dv = dinv[d];
    const float* af = (const float*)a;     // feats c*8 .. c*8+7
    float v8[8];
#pragma unroll
    for (int j = 0; j < 8; j++) v8[j] = af[j] * dv + b2[c * 8 + j];

    float m = v8[0];
#pragma unroll
    for (int j = 1; j < 8; j++) m = fmaxf(m, v8[j]);
    m = fmaxf(m, __shfl_xor(m, 1, 64));    // combine c-halves
    float e = 0.0f;
#pragma unroll
    for (int j = 0; j < 8; j++) e += expf(v8[j] - m);
    e += __shfl_xor(e, 1, 64);
    float lse = m + logf(e);

    if (g == 0) {
        float4 o0 = make_float4(v8[0] - lse, v8[1] - lse, v8[2] - lse, v8[3] - lse);
        float4 o1 = make_float4(v8[4] - lse, v8[5] - lse, v8[6] - lse, v8[7] - lse);
        float4* op = (float4*)(out + (size_t)d * 16 + c * 8);
        op[0] = o0; op[1] = o1;
    }
}

extern "C" void kernel_launch(void* const* d_in, const int* in_sizes, int n_in,
                              void* d_out, int out_size, void* d_ws, size_t ws_size,
                              hipStream_t stream) {
    const float* x  = (const float*)d_in[0];
    const int*  ei  = (const int*)d_in[1];
    const float* W1 = (const float*)d_in[2];
    const float* b1 = (const float*)d_in[3];
    const float* W2 = (const float*)d_in[4];
    const float* b2 = (const float*)d_in[5];
    float* out = (float*)d_out;

    const int N = in_sizes[0] / 128;   // 50000 (< 65536 required for uint packing)
    const int E = in_sizes[1] / 2;     // 800000
    const int* src = ei;
    const int* dst = ei + E;
    const int nbuckets = (N + 255) >> NBUCKET_SHIFT;   // 196 (< 256 required)
    const int nbins = (E + BIN_CHUNK - 1) / BIN_CHUNK; // 196
    const int g1blocks = (N + 63) / 64;                // 782 gemm1 blocks

    // Workspace layout (4B units):
    //   dinv    : N+16 floats (dinv[N] = 0)
    //   rowptr  : N ints (padded starts)
    //   rowcnt  : N ints (padded degrees, x8)
    //   bcur    : 256 ints   \ single memset region (bcur + h2acc)
    //   h2acc   : (N+1)*16 f32/
    //   ptot    : 256 ints (written by K2, no zeroing)
    //   dinv16  : (N+16)/2 ints as ushort table (written by K2)
    //   colsrc  : nbuckets*CCAP uints (5.4 MB, packed src|fp16(dinv) after K2b)
    //   pairs   : nbuckets*CAP uints (4.0 MB; dead after K2 -> h2h overlays)
    //   h1b     : 2 planes x (N+1)*16 uints (6.4 MB; 64B fp8 rows; row N = 0)
    float*          wsf     = (float*)d_ws;
    float*          dinv    = wsf;
    int*            rowptr  = (int*)(wsf + N + 16);
    int*            rowcnt  = rowptr + N;
    int*            bcur    = rowcnt + N;
    float*          h2acc   = (float*)(bcur + 256);
    int*            ptot    = (int*)(h2acc + (size_t)(N + 1) * 16);
    unsigned short* dinv16  = (unsigned short*)(ptot + 256);
    unsigned*       colsrc  = (unsigned*)(ptot + 256 + (N + 16) / 2);
    unsigned*       pairs   = colsrc + (size_t)nbuckets * CCAP;
    unsigned*       h1b     = pairs + (size_t)nbuckets * CAP;
    unsigned*       h2h     = pairs;   // overlays dead pairs (1.6 MB of 4.0 MB)

    // ---- K1: bin (blocks [0,nbins)) || gemm1 (blocks [nbins,nbins+g1blocks)) ----
    hipMemsetAsync(bcur, 0, (256 + (size_t)(N + 1) * 16) * sizeof(int), stream);
    bin_gemm1_kernel<<<nbins + g1blocks, 256, 0, stream>>>(src, dst, bcur, pairs,
                                                           E, nbuckets, nbins,
                                                           x, W1, h1b, N);

    // ---- K2: CSR build (rowptr/rowcnt/dinv/dinv16/ptot/colsrc) ----
    bucket_build_kernel<<<nbuckets, 256, 0, stream>>>(bcur, pairs, rowptr, rowcnt,
                                                      dinv, dinv16, ptot, colsrc,
                                                      h1b, N, nbuckets);

    // ---- K2b: pack fp16 weights into colsrc (streaming, in-place) ----
    pack_kernel<<<nbuckets * PSTRIPES, 256, 0, stream>>>(ptot, dinv16, colsrc,
                                                         nbuckets);

    // ---- K3: plane-split layer-1 pull + partial gemm2 (f32 atomics) ----
    l1_fused_kernel<<<((N + 15) / 16) * 2, 256, 0, stream>>>(rowptr, rowcnt, colsrc,
                                                             dinv, h1b, b1, W2,
                                                             h2acc, N);

    // ---- K3b: h2h = fp16(h2acc * dinv)  (prescaled 32 B rows for l2) ----
    h2cvt_kernel<<<((N + 1) * 4 + 255) / 256, 256, 0, stream>>>(h2acc, dinv, h2h, N);

    // ---- K4: fused pull-aggregation 2 + bias + log_softmax ----
    l2_kernel<<<(N + 15) / 16, 256, 0, stream>>>(rowptr, rowcnt, colsrc, dinv, h2h,
                                                 b2, out, N);
}

// Round 12
// 163.306 us; speedup vs baseline: 1.1103x; 1.0121x over previous
//
#include <hip/hip_runtime.h>
#include <hip/hip_fp16.h>
#include <math.h>

// GCN, N=50000 nodes, E=800000 edges, F_IN=128, H=128, C=16. f32 in/out; edges int32.
//
// R2-R21: CSR-by-dst pull, MFMA gemm1, fused gemm2, fp8 h1 gathers, pad-8 CSR,
// single-pass binning, bin||gemm1 one dispatch, per-edge dinv fma.
// R24: R21 l1 + pad-8 (160.3). R25: plane-split h1 (2x 3.2MB feature halves,
// per-XCD L2-resident) + f32 h2acc atomics (158.9) -- the ONLY l1 lever that
// paid; mechanism = smaller per-XCD gather set -> L2 hit rate. R27: fp16 l2
// via h2cvt, split-A dropped (158.7). R28 (deg atomics in K1) and R29 (packed
// colsrc) both REGRESSED -> request-count/byte theories dead; reverted.
// R30: R27 verbatim + extend the PROVEN residency mechanism: colsrc loads in
//      l1/l2 are NON-TEMPORAL (l1 streams colsrc twice, 10.8 MB, through the
//      same L2s holding the 3.2MB plane; plane-parity blocks share no L2 so
//      colsrc has zero L2 reuse -> nt is free and protects plane residency).
//      h2acc zeroing moved into bucket_build (memset 3.2MB -> 1KB).

#define NBUCKET_SHIFT 8                   // bucket = dst >> 8 (256 nodes/bucket)
#define BIN_CHUNK 4096                    // edges per binning block
#define PAD_SLOP (7 << NBUCKET_SHIFT)     // per-bucket padded slack (1792)
#define CAP  5120                         // per-bucket pairs capacity (mean 4096, sd 64)
#define CCAP (CAP + PAD_SLOP)             // per-bucket padded colsrc capacity (6912)

typedef __bf16 bf16x8 __attribute__((ext_vector_type(8)));
typedef float  f32x4  __attribute__((ext_vector_type(4)));
typedef float  f32x2  __attribute__((ext_vector_type(2)));

__device__ __forceinline__ unsigned short pack_bf16(float f) {
    unsigned u = __float_as_uint(f);
    return (unsigned short)((u + 0x7fffu + ((u >> 16) & 1u)) >> 16);   // RNE
}

// accumulate one 16 B chunk (16 fp8 features) scaled by w into 8 f32x2 regs
__device__ __forceinline__ void acc_fp8x16_fma(f32x2* a, uint4 v, float w) {
    f32x2 ww; ww.x = w; ww.y = w;
    a[0] += __builtin_amdgcn_cvt_pk_f32_fp8(v.x, false) * ww;
    a[1] += __builtin_amdgcn_cvt_pk_f32_fp8(v.x, true)  * ww;
    a[2] += __builtin_amdgcn_cvt_pk_f32_fp8(v.y, false) * ww;
    a[3] += __builtin_amdgcn_cvt_pk_f32_fp8(v.y, true)  * ww;
    a[4] += __builtin_amdgcn_cvt_pk_f32_fp8(v.z, false) * ww;
    a[5] += __builtin_amdgcn_cvt_pk_f32_fp8(v.z, true)  * ww;
    a[6] += __builtin_amdgcn_cvt_pk_f32_fp8(v.w, false) * ww;
    a[7] += __builtin_amdgcn_cvt_pk_f32_fp8(v.w, true)  * ww;
}

// accumulate one 16 B chunk (8 fp16 features) into 4 f32x2 regs
__device__ __forceinline__ void acc_fp16x8(f32x2* a, uint4 v) {
    float2 f;
    f = __half22float2(*(const __half2*)&v.x); a[0] += *(f32x2*)&f;
    f = __half22float2(*(const __half2*)&v.y); a[1] += *(f32x2*)&f;
    f = __half22float2(*(const __half2*)&v.z); a[2] += *(f32x2*)&f;
    f = __half22float2(*(const __half2*)&v.w); a[3] += *(f32x2*)&f;
}

// ---------------- K1: single-pass binning  ||  gemm1 MFMA (fused dispatch) ----
union K1Smem {
    struct { unsigned spair[BIN_CHUNK]; int lcnt[256]; int lbase[256]; } b; // 18 KB
    unsigned short wtp[16384];     // 32 KB  (gemm1 phase A)
    float outb[4][16 * 132];       // 33.8 KB (gemm1 phase B, reuses wtp space)
};

__global__ __launch_bounds__(256)
void bin_gemm1_kernel(const int* __restrict__ src, const int* __restrict__ dst,
                      int* __restrict__ bcur, unsigned* __restrict__ pairs,
                      int E, int nbuckets, int nbins,
                      const float* __restrict__ x, const float* __restrict__ W1,
                      unsigned* __restrict__ h1b, int N) {
    __shared__ K1Smem sm;
    const int blk = blockIdx.x;
    const int tid = threadIdx.x;

    if (blk < nbins) {                // ---------------- bin path
        const int e0 = blk * BIN_CHUNK;
        const int cnt = min(BIN_CHUNK, E - e0);
        sm.b.lcnt[tid] = 0;
        __syncthreads();
        for (int i = tid; i < cnt; i += 256) {
            unsigned s = (unsigned)src[e0 + i], d = (unsigned)dst[e0 + i];
            sm.b.spair[i] = (d >> NBUCKET_SHIFT) << 24 | (d & 255u) << 16 | s;
            atomicAdd(&sm.b.lcnt[d >> NBUCKET_SHIFT], 1);
        }
        __syncthreads();
        if (tid < nbuckets) {
            int c = sm.b.lcnt[tid];
            sm.b.lbase[tid] = (c > 0) ? atomicAdd(&bcur[tid], c) : 0;
            sm.b.lcnt[tid] = 0;       // reuse as local cursor
        }
        __syncthreads();
        for (int i = tid; i < cnt; i += 256) {
            unsigned p = sm.b.spair[i];
            int b = (int)(p >> 24);
            int off = atomicAdd(&sm.b.lcnt[b], 1);
            pairs[b * CAP + sm.b.lbase[b] + off] = p;
        }
        return;
    }

    // ---------------- gemm1 path
    const int gblk = blk - nbins;
    const int wave = tid >> 6, lane = tid & 63;
    const int q = lane >> 4, m = lane & 15;
    const int row0 = gblk * 64 + wave * 16;
    const int row = row0 + m;
    const int rowc = (row < N) ? row : (N - 1);   // clamp (OOB rows masked at store)

    // phase A: pack W1 -> LDS bf16 fragment layout (coalesced global reads)
    for (int it = tid; it < 16384; it += 256) {
        int k = it >> 7, n = it & 127;            // W1[k][n], row-major
        int t = n >> 4, mm = n & 15;
        int ks = k >> 5;
        int lane2 = (((k & 31) >> 3) << 4) | mm;
        int j = k & 7;
        sm.wtp[(t * 4 + ks) * 512 + lane2 * 8 + j] = pack_bf16(W1[it]);
    }
    __syncthreads();

    f32x4 acc[8];
#pragma unroll
    for (int t = 0; t < 8; t++) acc[t] = (f32x4)0.0f;

#pragma unroll
    for (int ks = 0; ks < 4; ks++) {
        const float4* xp = (const float4*)(x + (size_t)rowc * 128 + ks * 32 + q * 8);
        float4 f0 = xp[0], f1 = xp[1];
        float fv[8] = {f0.x, f0.y, f0.z, f0.w, f1.x, f1.y, f1.z, f1.w};
        bf16x8 ah;
#pragma unroll
        for (int j = 0; j < 8; j++) ah[j] = (__bf16)fv[j];
#pragma unroll
        for (int t = 0; t < 8; t++) {
            bf16x8 b = *(const bf16x8*)(sm.wtp + (size_t)(t * 4 + ks) * 512 + lane * 8);
            acc[t] = __builtin_amdgcn_mfma_f32_16x16x32_bf16(ah, b, acc[t], 0, 0, 0);
        }
    }
    __syncthreads();   // all waves done reading wtp before outb aliases it

#pragma unroll
    for (int t = 0; t < 8; t++)
#pragma unroll
        for (int r = 0; r < 4; r++)
            sm.outb[wave][(q * 4 + r) * 132 + t * 16 + m] = acc[t][r];
    __syncthreads();

    const int r2 = lane >> 2, j = lane & 3;
    const int orow = row0 + r2;
    if (orow < N) {
        const float* lrow = &sm.outb[wave][r2 * 132];
#pragma unroll
        for (int s = 0; s < 4; s++) {
            float4 a = *(const float4*)(lrow + s * 32 + j * 8);
            float4 b = *(const float4*)(lrow + s * 32 + j * 8 + 4);
            unsigned lo = __builtin_amdgcn_cvt_pk_fp8_f32(a.x, a.y, 0, false);
            lo = __builtin_amdgcn_cvt_pk_fp8_f32(a.z, a.w, lo, true);
            unsigned hi = __builtin_amdgcn_cvt_pk_fp8_f32(b.x, b.y, 0, false);
            hi = __builtin_amdgcn_cvt_pk_fp8_f32(b.z, b.w, hi, true);
            // feats s*32+j*8 ..+7; plane = s>>1, within-plane uint2 slot (s&1)*4+j
            ((uint2*)h1b)[((size_t)(s >> 1) * (N + 1) + orow) * 8 + (s & 1) * 4 + j]
                = make_uint2(lo, hi);
        }
    }
}

// ---------------- K2: per-bucket padded rowptr + dinv + colsrc ---------------
// Pad each node's list to a multiple of 8. Dummy slots -> index N (zeroed rows,
// dinv[N] = 0 so their fma contribution is exactly 0). Also zeroes this
// bucket's h2acc rows (replaces the 3.2MB launch-side memset).
__global__ __launch_bounds__(256)
void bucket_build_kernel(const int* __restrict__ bcur, const unsigned* __restrict__ pairs,
                         int* __restrict__ rowptr, int* __restrict__ rowcnt,
                         float* __restrict__ dinv, int* __restrict__ colsrc,
                         unsigned* __restrict__ h1b, float* __restrict__ h2acc,
                         int N, int nbuckets) {
    __shared__ int cnt[256];
    __shared__ int sm[256];
    const int tid = threadIdx.x;
    const int blk = blockIdx.x;
    const int nb0 = blk << NBUCKET_SHIFT;

    if (blk == 0) {                   // zero the dummy rows (fresh each run)
        if (tid < 16) h1b[((size_t)0 * (N + 1) + N) * 16 + tid] = 0u;       // plane 0
        else if (tid < 32) h1b[((size_t)1 * (N + 1) + N) * 16 + (tid - 16)] = 0u; // plane 1
        else if (tid == 32) dinv[N] = 0.0f;
    }
    {   // zero this bucket's h2acc rows (one row per thread, 4 float4 stores)
        int node = nb0 + tid;
        if (node <= N) {
            float4* hz = (float4*)(h2acc + (size_t)node * 16);
            float4 z = make_float4(0.f, 0.f, 0.f, 0.f);
            hz[0] = z; hz[1] = z; hz[2] = z; hz[3] = z;
        }
    }

    const int lo = blk * CAP;
    const int hi = lo + bcur[blk];
    cnt[tid] = 0;
    __syncthreads();

    for (int i = lo + tid; i < hi; i += 256)
        atomicAdd(&cnt[(int)(pairs[i] >> 16) & 255], 1);
    __syncthreads();

    int v = cnt[tid];                  // real degree of this node
    int pdeg = (v + 7) & ~7;           // padded to x8
    sm[tid] = pdeg;
    __syncthreads();
#pragma unroll
    for (int off = 1; off < 256; off <<= 1) {
        int u = (tid >= off) ? sm[tid - off] : 0;
        __syncthreads();
        sm[tid] += u;
        __syncthreads();
    }
    int pexcl = sm[tid] - pdeg;
    const int start = blk * CCAP + pexcl;
    int node = nb0 + tid;
    if (node < N) {
        rowptr[node] = start;
        rowcnt[node] = pdeg;
        dinv[node] = rsqrtf((float)v + 1.0f);   // +1 self-loop
    }
    __syncthreads();
    cnt[tid] = start;   // reuse as scatter cursor
    __syncthreads();
    for (int i = lo + tid; i < hi; i += 256) {
        unsigned p = pairs[i];
        int pos = atomicAdd(&cnt[(int)(p >> 16) & 255], 1);
        colsrc[pos] = (int)(p & 0xffffu);
    }
    for (int p = start + v; p < start + pdeg; ++p)   // dummy fill (<=7/node)
        colsrc[p] = N;
}

// ---------------- K3: plane-split layer-1 pull + partial gemm2 ----------------
// Block 2b+p: node set b (16 nodes), feature plane p (64 feats, 64B rows).
// Lane = node n (bits 4-5) x edge-group g (bits 2-3) x 16B chunk c (bits 0-1).
// 16-edge batches, 4 gathers in flight, index prefetch; 4-edge sub-loop for the
// pad-8 remainder. colsrc is streamed NON-TEMPORALLY (zero L2 reuse across
// plane-parity XCDs) to keep the 3.2MB plane L2-resident.
__global__ __launch_bounds__(256)
void l1_fused_kernel(const int* __restrict__ rowptr, const int* __restrict__ rowcnt,
                     const int* __restrict__ colsrc,
                     const float* __restrict__ dinv, const unsigned* __restrict__ h1b,
                     const float* __restrict__ b1, const float* __restrict__ W2,
                     float* __restrict__ h2acc, int N) {
    __shared__ float rows[4][4][68];   // [wave][node][feat(+pad)], 4.25 KB
    __shared__ float w2s[64 * 16];     // plane's W2 half [k][col], 4 KB
    const int tid = threadIdx.x;
    const int wave = tid >> 6, lane = tid & 63;
    const int c = lane & 3;            // 16B chunk 0..3 (plane feats c*16..+15)
    const int g = (lane >> 2) & 3;     // edge group 0..3
    const int n = lane >> 4;           // node 0..3 within wave
    const int p = blockIdx.x & 1;      // feature plane
    const int d = (blockIdx.x >> 1) * 16 + wave * 4 + n;

    for (int i = tid; i < 256; i += 256)          // 64x16 floats = 256 float4
        ((float4*)w2s)[i] = ((const float4*)W2)[p * 256 + i];

    const uint4* hq = (const uint4*)h1b + (size_t)p * (N + 1) * 4;  // row = 4 uint4

    if (d < N) {
        const float dvd = dinv[d];
        f32x2 a[8];
#pragma unroll
        for (int j = 0; j < 8; j++) a[j] = (f32x2)0.0f;

        if (g == 0)                   // self-loop term: h1[d] * dinv[d]
            acc_fp8x16_fma(a, hq[(size_t)d * 4 + c], dvd);

        int i = rowptr[d];
        const int end = i + rowcnt[d];     // multiple of 8
        int s0 = 0, s1 = 0, s2 = 0, s3 = 0;
        if (i + 16 <= end) {
            s0 = __builtin_nontemporal_load(colsrc + i + g);
            s1 = __builtin_nontemporal_load(colsrc + i + g + 4);
            s2 = __builtin_nontemporal_load(colsrc + i + g + 8);
            s3 = __builtin_nontemporal_load(colsrc + i + g + 12);
        }
        while (i + 16 <= end) {
            uint4 v0 = hq[(size_t)s0 * 4 + c];
            uint4 v1 = hq[(size_t)s1 * 4 + c];
            uint4 v2 = hq[(size_t)s2 * 4 + c];
            uint4 v3 = hq[(size_t)s3 * 4 + c];
            float w0 = dinv[s0], w1 = dinv[s1], w2 = dinv[s2], w3 = dinv[s3];
            i += 16;
            if (i + 16 <= end) {          // prefetch next batch's indices
                s0 = __builtin_nontemporal_load(colsrc + i + g);
                s1 = __builtin_nontemporal_load(colsrc + i + g + 4);
                s2 = __builtin_nontemporal_load(colsrc + i + g + 8);
                s3 = __builtin_nontemporal_load(colsrc + i + g + 12);
            }
            acc_fp8x16_fma(a, v0, w0); acc_fp8x16_fma(a, v1, w1);
            acc_fp8x16_fma(a, v2, w2); acc_fp8x16_fma(a, v3, w3);
        }
        for (; i + 4 <= end; i += 4) {    // 8-edge pad remainder (0 or 2 iters)
            int sx = __builtin_nontemporal_load(colsrc + i + g);
            acc_fp8x16_fma(a, hq[(size_t)sx * 4 + c], dinv[sx]);
        }

#pragma unroll
        for (int j = 0; j < 8; j++) { // combine the 4 edge groups (bits 2-3)
            a[j].x += __shfl_xor(a[j].x, 4, 64);
            a[j].y += __shfl_xor(a[j].y, 4, 64);
            a[j].x += __shfl_xor(a[j].x, 8, 64);
            a[j].y += __shfl_xor(a[j].y, 8, 64);
        }

        if (g == 0) {                 // relu(dinv*agg + b1-half) -> LDS row
            float* rbase = &rows[wave][n][c * 16];
#pragma unroll
            for (int t = 0; t < 4; t++) {
                float4 bb = ((const float4*)b1)[p * 16 + c * 4 + t];
                float4 o;
                o.x = fmaxf(a[2 * t].x * dvd + bb.x, 0.0f);
                o.y = fmaxf(a[2 * t].y * dvd + bb.y, 0.0f);
                o.z = fmaxf(a[2 * t + 1].x * dvd + bb.z, 0.0f);
                o.w = fmaxf(a[2 * t + 1].y * dvd + bb.w, 0.0f);
                *(float4*)(rbase + 4 * t) = o;
            }
        }
    }
    __syncthreads();

    // partial gemm2: lane = node n2 (bits 4-5) x col (bits 0-3); 64-k dot.
    const int n2 = lane >> 4, col = lane & 15;
    const int d2 = (blockIdx.x >> 1) * 16 + wave * 4 + n2;
    if (d2 < N) {
        const float* r = &rows[wave][n2][0];
        float p0 = 0.0f, p1 = 0.0f;
#pragma unroll
        for (int k = 0; k < 32; k++) {       // 2-way ILP
            p0 = fmaf(r[k],      w2s[k * 16 + col],        p0);
            p1 = fmaf(r[k + 32], w2s[(k + 32) * 16 + col], p1);
        }
        atomicAdd(&h2acc[(size_t)d2 * 16 + col], p0 + p1);
    }
}

// ---------------- K3b: h2 convert  h2h[s] = fp16(h2acc[s] * dinv[s]) ---------
__global__ __launch_bounds__(256)
void h2cvt_kernel(const float* __restrict__ h2acc, const float* __restrict__ dinv,
                  unsigned* __restrict__ h2h, int N) {
    int idx = blockIdx.x * 256 + threadIdx.x;   // one float4 = quarter row
    if (idx >= (N + 1) * 4) return;
    float dv = dinv[idx >> 2];
    float4 v = ((const float4*)h2acc)[idx];
    __half2 lo = __floats2half2_rn(v.x * dv, v.y * dv);
    __half2 hi = __floats2half2_rn(v.z * dv, v.w * dv);
    ((uint2*)h2h)[idx] = make_uint2(*(unsigned*)&lo, *(unsigned*)&hi);
}

// ---------------- K4: fused layer-2 pull + log_softmax (fp16 gathers) ---------
// Lane = node n (bits 4-5) x edge-group g (bits 1-3) x 16B chunk c (bit 0).
// Batch = 8 edges/node (pad-8); 2-deep gather pipeline. Rows PRESCALED by
// dinv[s]; colsrc streamed non-temporally.
__global__ __launch_bounds__(256)
void l2_kernel(const int* __restrict__ rowptr, const int* __restrict__ rowcnt,
               const int* __restrict__ colsrc,
               const float* __restrict__ dinv, const unsigned* __restrict__ h2s,
               const float* __restrict__ b2, float* __restrict__ out, int N) {
    const int tid = threadIdx.x;
    const int wave = tid >> 6, lane = tid & 63;
    const int n = lane >> 4;          // node 0..3 within wave
    const int g = (lane >> 1) & 7;    // edge group 0..7
    const int c = lane & 1;           // 16B chunk (8 fp16 feats, c*8..c*8+7)
    const int d = blockIdx.x * 16 + wave * 4 + n;
    if (d >= N) return;
    const uint4* h2q = (const uint4*)h2s;   // node row = 2 uint4 (32 B)

    f32x2 a[4];
#pragma unroll
    for (int j = 0; j < 4; j++) a[j] = (f32x2)0.0f;

    if (g == 0)                        // self-loop term (prescaled by dinv[d])
        acc_fp16x8(a, h2q[(size_t)d * 2 + c]);

    int i = rowptr[d];
    const int end = i + rowcnt[d];     // multiple of 8
    uint4 v; int s2 = 0;
    if (i < end) {
        int s = __builtin_nontemporal_load(colsrc + i + g);
        v = h2q[(size_t)s * 2 + c];
    }
    if (i + 8 < end) s2 = __builtin_nontemporal_load(colsrc + i + 8 + g);
    while (i < end) {
        uint4 vc = v;
        if (i + 8 < end) v = h2q[(size_t)s2 * 2 + c];
        if (i + 16 < end) s2 = __builtin_nontemporal_load(colsrc + i + 16 + g);
        i += 8;
        acc_fp16x8(a, vc);
    }

#pragma unroll
    for (int j = 0; j < 4; j++) {      // combine the 8 edge groups (bits 1-3)
#pragma unroll
        for (int off = 2; off <= 8; off <<= 1) {
            a[j].x += __shfl_xor(a[j].x, off, 64);
            a[j].y += __shfl_xor(a[j].y, off, 64);
        }
    }

    const float dv = dinv[d];
    const float* af = (const float*)a;     // feats c*8 .. c*8+7
    float v8[8];
#pragma unroll
    for (int j = 0; j < 8; j++) v8[j] = af[j] * dv + b2[c * 8 + j];

    float m = v8[0];
#pragma unroll
    for (int j = 1; j < 8; j++) m = fmaxf(m, v8[j]);
    m = fmaxf(m, __shfl_xor(m, 1, 64));    // combine c-halves
    float e = 0.0f;
#pragma unroll
    for (int j = 0; j < 8; j++) e += expf(v8[j] - m);
    e += __shfl_xor(e, 1, 64);
    float lse = m + logf(e);

    if (g == 0) {
        float4 o0 = make_float4(v8[0] - lse, v8[1] - lse, v8[2] - lse, v8[3] - lse);
        float4 o1 = make_float4(v8[4] - lse, v8[5] - lse, v8[6] - lse, v8[7] - lse);
        float4* op = (float4*)(out + (size_t)d * 16 + c * 8);
        op[0] = o0; op[1] = o1;
    }
}

extern "C" void kernel_launch(void* const* d_in, const int* in_sizes, int n_in,
                              void* d_out, int out_size, void* d_ws, size_t ws_size,
                              hipStream_t stream) {
    const float* x  = (const float*)d_in[0];
    const int*  ei  = (const int*)d_in[1];
    const float* W1 = (const float*)d_in[2];
    const float* b1 = (const float*)d_in[3];
    const float* W2 = (const float*)d_in[4];
    const float* b2 = (const float*)d_in[5];
    float* out = (float*)d_out;

    const int N = in_sizes[0] / 128;   // 50000 (< 65536 required for uint packing)
    const int E = in_sizes[1] / 2;     // 800000
    const int* src = ei;
    const int* dst = ei + E;
    const int nbuckets = (N + 255) >> NBUCKET_SHIFT;   // 196 (< 256 required)
    const int nbins = (E + BIN_CHUNK - 1) / BIN_CHUNK; // 196
    const int g1blocks = (N + 63) / 64;                // 782 gemm1 blocks

    // Workspace layout (4B units):
    //   dinv    : N+16 floats (dinv[N] = 0)
    //   rowptr  : N ints (padded starts)
    //   rowcnt  : N ints (padded degrees, x8)
    //   bcur    : 256 ints (1 KB memset -- h2acc zeroed inside bucket_build)
    //   h2acc   : (N+1)*16 f32 (3.2 MB, gemm2 partial accumulator)
    //   colsrc  : nbuckets*CCAP ints (5.4 MB)
    //   pairs   : nbuckets*CAP uints (4.0 MB; dead after K2 -> h2h overlays)
    //   h1b     : 2 planes x (N+1)*16 uints (6.4 MB; 64B fp8 rows; row N = 0)
    float*          wsf     = (float*)d_ws;
    float*          dinv    = wsf;
    int*            rowptr  = (int*)(wsf + N + 16);
    int*            rowcnt  = rowptr + N;
    int*            bcur    = rowcnt + N;
    float*          h2acc   = (float*)(bcur + 256);
    int*            colsrc  = (int*)(h2acc + (size_t)(N + 1) * 16);
    unsigned*       pairs   = (unsigned*)(colsrc + (size_t)nbuckets * CCAP);
    unsigned*       h1b     = pairs + (size_t)nbuckets * CAP;
    unsigned*       h2h     = pairs;   // overlays dead pairs (1.6 MB of 4.0 MB)

    // ---- K1: bin (blocks [0,nbins)) || gemm1 (blocks [nbins,nbins+g1blocks)) ----
    hipMemsetAsync(bcur, 0, 256 * sizeof(int), stream);
    bin_gemm1_kernel<<<nbins + g1blocks, 256, 0, stream>>>(src, dst, bcur, pairs,
                                                           E, nbuckets, nbins,
                                                           x, W1, h1b, N);

    // ---- K2: CSR build (rowptr/rowcnt/dinv/colsrc) + h2acc zeroing ----
    bucket_build_kernel<<<nbuckets, 256, 0, stream>>>(bcur, pairs, rowptr, rowcnt,
                                                      dinv, colsrc, h1b, h2acc,
                                                      N, nbuckets);

    // ---- K3: plane-split layer-1 pull + partial gemm2 (f32 atomics) ----
    l1_fused_kernel<<<((N + 15) / 16) * 2, 256, 0, stream>>>(rowptr, rowcnt, colsrc,
                                                             dinv, h1b, b1, W2,
                                                             h2acc, N);

    // ---- K3b: h2h = fp16(h2acc * dinv)  (prescaled 32 B rows for l2) ----
    h2cvt_kernel<<<((N + 1) * 4 + 255) / 256, 256, 0, stream>>>(h2acc, dinv, h2h, N);

    // ---- K4: fused pull-aggregation 2 + bias + log_softmax ----
    l2_kernel<<<(N + 15) / 16, 256, 0, stream>>>(rowptr, rowcnt, colsrc, dinv, h2h,
                                                 b2, out, N);
}

// Round 13
// 158.109 us; speedup vs baseline: 1.1468x; 1.0329x over previous
//
#include <hip/hip_runtime.h>
#include <hip/hip_fp16.h>
#include <math.h>

// GCN, N=50000 nodes, E=800000 edges, F_IN=128, H=128, C=16. f32 in/out; edges int32.
//
// FINAL (R31 = R27 verbatim, best measured 158.65us):
// R2-R21: CSR-by-dst pull, MFMA gemm1, fused gemm2, fp8 h1 gathers, pad-8 CSR,
// single-pass binning, bin||gemm1 one dispatch, per-edge dinv fma.
// R24: R21 l1 + pad-8 (160.3). R25: plane-split h1 (2x 3.2MB feature halves,
// per-XCD L2-resident) + f32 h2acc atomics (158.9) -- the one l1 lever that
// paid (smaller per-XCD gather set -> L2 hit rate). R27: fp16 l2 via h2cvt,
// split-A dropped (158.65, BEST).
// Refuted levers (all measured): gather volume (R19/R24), wave layout/MLP
// (R22/R23 regressed), payload bytes (R27 flat), request count (R28/R29
// regressed), nt cache hints (R30 regressed). l1 sits at the hardware's
// sustained random-gather throughput; remaining spread is run noise.

#define NBUCKET_SHIFT 8                   // bucket = dst >> 8 (256 nodes/bucket)
#define BIN_CHUNK 4096                    // edges per binning block
#define PAD_SLOP (7 << NBUCKET_SHIFT)     // per-bucket padded slack (1792)
#define CAP  5120                         // per-bucket pairs capacity (mean 4096, sd 64)
#define CCAP (CAP + PAD_SLOP)             // per-bucket padded colsrc capacity (6912)

typedef __bf16 bf16x8 __attribute__((ext_vector_type(8)));
typedef float  f32x4  __attribute__((ext_vector_type(4)));
typedef float  f32x2  __attribute__((ext_vector_type(2)));

__device__ __forceinline__ unsigned short pack_bf16(float f) {
    unsigned u = __float_as_uint(f);
    return (unsigned short)((u + 0x7fffu + ((u >> 16) & 1u)) >> 16);   // RNE
}

// accumulate one 16 B chunk (16 fp8 features) scaled by w into 8 f32x2 regs
__device__ __forceinline__ void acc_fp8x16_fma(f32x2* a, uint4 v, float w) {
    f32x2 ww; ww.x = w; ww.y = w;
    a[0] += __builtin_amdgcn_cvt_pk_f32_fp8(v.x, false) * ww;
    a[1] += __builtin_amdgcn_cvt_pk_f32_fp8(v.x, true)  * ww;
    a[2] += __builtin_amdgcn_cvt_pk_f32_fp8(v.y, false) * ww;
    a[3] += __builtin_amdgcn_cvt_pk_f32_fp8(v.y, true)  * ww;
    a[4] += __builtin_amdgcn_cvt_pk_f32_fp8(v.z, false) * ww;
    a[5] += __builtin_amdgcn_cvt_pk_f32_fp8(v.z, true)  * ww;
    a[6] += __builtin_amdgcn_cvt_pk_f32_fp8(v.w, false) * ww;
    a[7] += __builtin_amdgcn_cvt_pk_f32_fp8(v.w, true)  * ww;
}

// accumulate one 16 B chunk (8 fp16 features) into 4 f32x2 regs
__device__ __forceinline__ void acc_fp16x8(f32x2* a, uint4 v) {
    float2 f;
    f = __half22float2(*(const __half2*)&v.x); a[0] += *(f32x2*)&f;
    f = __half22float2(*(const __half2*)&v.y); a[1] += *(f32x2*)&f;
    f = __half22float2(*(const __half2*)&v.z); a[2] += *(f32x2*)&f;
    f = __half22float2(*(const __half2*)&v.w); a[3] += *(f32x2*)&f;
}

// ---------------- K1: single-pass binning  ||  gemm1 MFMA (fused dispatch) ----
union K1Smem {
    struct { unsigned spair[BIN_CHUNK]; int lcnt[256]; int lbase[256]; } b; // 18 KB
    unsigned short wtp[16384];     // 32 KB  (gemm1 phase A)
    float outb[4][16 * 132];       // 33.8 KB (gemm1 phase B, reuses wtp space)
};

__global__ __launch_bounds__(256)
void bin_gemm1_kernel(const int* __restrict__ src, const int* __restrict__ dst,
                      int* __restrict__ bcur, unsigned* __restrict__ pairs,
                      int E, int nbuckets, int nbins,
                      const float* __restrict__ x, const float* __restrict__ W1,
                      unsigned* __restrict__ h1b, int N) {
    __shared__ K1Smem sm;
    const int blk = blockIdx.x;
    const int tid = threadIdx.x;

    if (blk < nbins) {                // ---------------- bin path
        const int e0 = blk * BIN_CHUNK;
        const int cnt = min(BIN_CHUNK, E - e0);
        sm.b.lcnt[tid] = 0;
        __syncthreads();
        for (int i = tid; i < cnt; i += 256) {
            unsigned s = (unsigned)src[e0 + i], d = (unsigned)dst[e0 + i];
            sm.b.spair[i] = (d >> NBUCKET_SHIFT) << 24 | (d & 255u) << 16 | s;
            atomicAdd(&sm.b.lcnt[d >> NBUCKET_SHIFT], 1);
        }
        __syncthreads();
        if (tid < nbuckets) {
            int c = sm.b.lcnt[tid];
            sm.b.lbase[tid] = (c > 0) ? atomicAdd(&bcur[tid], c) : 0;
            sm.b.lcnt[tid] = 0;       // reuse as local cursor
        }
        __syncthreads();
        for (int i = tid; i < cnt; i += 256) {
            unsigned p = sm.b.spair[i];
            int b = (int)(p >> 24);
            int off = atomicAdd(&sm.b.lcnt[b], 1);
            pairs[b * CAP + sm.b.lbase[b] + off] = p;
        }
        return;
    }

    // ---------------- gemm1 path
    const int gblk = blk - nbins;
    const int wave = tid >> 6, lane = tid & 63;
    const int q = lane >> 4, m = lane & 15;
    const int row0 = gblk * 64 + wave * 16;
    const int row = row0 + m;
    const int rowc = (row < N) ? row : (N - 1);   // clamp (OOB rows masked at store)

    // phase A: pack W1 -> LDS bf16 fragment layout (coalesced global reads)
    for (int it = tid; it < 16384; it += 256) {
        int k = it >> 7, n = it & 127;            // W1[k][n], row-major
        int t = n >> 4, mm = n & 15;
        int ks = k >> 5;
        int lane2 = (((k & 31) >> 3) << 4) | mm;
        int j = k & 7;
        sm.wtp[(t * 4 + ks) * 512 + lane2 * 8 + j] = pack_bf16(W1[it]);
    }
    __syncthreads();

    f32x4 acc[8];
#pragma unroll
    for (int t = 0; t < 8; t++) acc[t] = (f32x4)0.0f;

#pragma unroll
    for (int ks = 0; ks < 4; ks++) {
        const float4* xp = (const float4*)(x + (size_t)rowc * 128 + ks * 32 + q * 8);
        float4 f0 = xp[0], f1 = xp[1];
        float fv[8] = {f0.x, f0.y, f0.z, f0.w, f1.x, f1.y, f1.z, f1.w};
        bf16x8 ah;
#pragma unroll
        for (int j = 0; j < 8; j++) ah[j] = (__bf16)fv[j];
#pragma unroll
        for (int t = 0; t < 8; t++) {
            bf16x8 b = *(const bf16x8*)(sm.wtp + (size_t)(t * 4 + ks) * 512 + lane * 8);
            acc[t] = __builtin_amdgcn_mfma_f32_16x16x32_bf16(ah, b, acc[t], 0, 0, 0);
        }
    }
    __syncthreads();   // all waves done reading wtp before outb aliases it

#pragma unroll
    for (int t = 0; t < 8; t++)
#pragma unroll
        for (int r = 0; r < 4; r++)
            sm.outb[wave][(q * 4 + r) * 132 + t * 16 + m] = acc[t][r];
    __syncthreads();

    const int r2 = lane >> 2, j = lane & 3;
    const int orow = row0 + r2;
    if (orow < N) {
        const float* lrow = &sm.outb[wave][r2 * 132];
#pragma unroll
        for (int s = 0; s < 4; s++) {
            float4 a = *(const float4*)(lrow + s * 32 + j * 8);
            float4 b = *(const float4*)(lrow + s * 32 + j * 8 + 4);
            unsigned lo = __builtin_amdgcn_cvt_pk_fp8_f32(a.x, a.y, 0, false);
            lo = __builtin_amdgcn_cvt_pk_fp8_f32(a.z, a.w, lo, true);
            unsigned hi = __builtin_amdgcn_cvt_pk_fp8_f32(b.x, b.y, 0, false);
            hi = __builtin_amdgcn_cvt_pk_fp8_f32(b.z, b.w, hi, true);
            // feats s*32+j*8 ..+7; plane = s>>1, within-plane uint2 slot (s&1)*4+j
            ((uint2*)h1b)[((size_t)(s >> 1) * (N + 1) + orow) * 8 + (s & 1) * 4 + j]
                = make_uint2(lo, hi);
        }
    }
}

// ---------------- K2: per-bucket padded rowptr + dinv + colsrc ---------------
// Pad each node's list to a multiple of 8. Dummy slots -> index N (zeroed rows,
// dinv[N] = 0 so their fma contribution is exactly 0).
__global__ __launch_bounds__(256)
void bucket_build_kernel(const int* __restrict__ bcur, const unsigned* __restrict__ pairs,
                         int* __restrict__ rowptr, int* __restrict__ rowcnt,
                         float* __restrict__ dinv, int* __restrict__ colsrc,
                         unsigned* __restrict__ h1b, int N, int nbuckets) {
    __shared__ int cnt[256];
    __shared__ int sm[256];
    const int tid = threadIdx.x;
    const int blk = blockIdx.x;
    const int nb0 = blk << NBUCKET_SHIFT;

    if (blk == 0) {                   // zero the dummy rows (fresh each run)
        if (tid < 16) h1b[((size_t)0 * (N + 1) + N) * 16 + tid] = 0u;       // plane 0
        else if (tid < 32) h1b[((size_t)1 * (N + 1) + N) * 16 + (tid - 16)] = 0u; // plane 1
        else if (tid == 32) dinv[N] = 0.0f;
        // h2acc row N zeroed by launch-side memset.
    }

    const int lo = blk * CAP;
    const int hi = lo + bcur[blk];
    cnt[tid] = 0;
    __syncthreads();

    for (int i = lo + tid; i < hi; i += 256)
        atomicAdd(&cnt[(int)(pairs[i] >> 16) & 255], 1);
    __syncthreads();

    int v = cnt[tid];                  // real degree of this node
    int pdeg = (v + 7) & ~7;           // padded to x8
    sm[tid] = pdeg;
    __syncthreads();
#pragma unroll
    for (int off = 1; off < 256; off <<= 1) {
        int u = (tid >= off) ? sm[tid - off] : 0;
        __syncthreads();
        sm[tid] += u;
        __syncthreads();
    }
    int pexcl = sm[tid] - pdeg;
    const int start = blk * CCAP + pexcl;
    int node = nb0 + tid;
    if (node < N) {
        rowptr[node] = start;
        rowcnt[node] = pdeg;
        dinv[node] = rsqrtf((float)v + 1.0f);   // +1 self-loop
    }
    __syncthreads();
    cnt[tid] = start;   // reuse as scatter cursor
    __syncthreads();
    for (int i = lo + tid; i < hi; i += 256) {
        unsigned p = pairs[i];
        int pos = atomicAdd(&cnt[(int)(p >> 16) & 255], 1);
        colsrc[pos] = (int)(p & 0xffffu);
    }
    for (int p = start + v; p < start + pdeg; ++p)   // dummy fill (<=7/node)
        colsrc[p] = N;
}

// ---------------- K3: plane-split layer-1 pull + partial gemm2 ----------------
// Block 2b+p: node set b (16 nodes), feature plane p (64 feats, 64B rows).
// Lane = node n (bits 4-5) x edge-group g (bits 2-3) x 16B chunk c (bits 0-1).
// 16-edge batches, 4 gathers in flight, index prefetch; 4-edge sub-loop for the
// pad-8 remainder. Per-XCD gather set = one 3.2MB plane (L2-resident under
// round-robin block->XCD dispatch). gemm2: 64-k partial -> f32 atomicAdd.
__global__ __launch_bounds__(256)
void l1_fused_kernel(const int* __restrict__ rowptr, const int* __restrict__ rowcnt,
                     const int* __restrict__ colsrc,
                     const float* __restrict__ dinv, const unsigned* __restrict__ h1b,
                     const float* __restrict__ b1, const float* __restrict__ W2,
                     float* __restrict__ h2acc, int N) {
    __shared__ float rows[4][4][68];   // [wave][node][feat(+pad)], 4.25 KB
    __shared__ float w2s[64 * 16];     // plane's W2 half [k][col], 4 KB
    const int tid = threadIdx.x;
    const int wave = tid >> 6, lane = tid & 63;
    const int c = lane & 3;            // 16B chunk 0..3 (plane feats c*16..+15)
    const int g = (lane >> 2) & 3;     // edge group 0..3
    const int n = lane >> 4;           // node 0..3 within wave
    const int p = blockIdx.x & 1;      // feature plane
    const int d = (blockIdx.x >> 1) * 16 + wave * 4 + n;

    for (int i = tid; i < 256; i += 256)          // 64x16 floats = 256 float4
        ((float4*)w2s)[i] = ((const float4*)W2)[p * 256 + i];

    const uint4* hq = (const uint4*)h1b + (size_t)p * (N + 1) * 4;  // row = 4 uint4

    if (d < N) {
        const float dvd = dinv[d];
        f32x2 a[8];
#pragma unroll
        for (int j = 0; j < 8; j++) a[j] = (f32x2)0.0f;

        if (g == 0)                   // self-loop term: h1[d] * dinv[d]
            acc_fp8x16_fma(a, hq[(size_t)d * 4 + c], dvd);

        int i = rowptr[d];
        const int end = i + rowcnt[d];     // multiple of 8
        int s0 = 0, s1 = 0, s2 = 0, s3 = 0;
        if (i + 16 <= end) {
            s0 = colsrc[i + g];      s1 = colsrc[i + g + 4];
            s2 = colsrc[i + g + 8];  s3 = colsrc[i + g + 12];
        }
        while (i + 16 <= end) {
            uint4 v0 = hq[(size_t)s0 * 4 + c];
            uint4 v1 = hq[(size_t)s1 * 4 + c];
            uint4 v2 = hq[(size_t)s2 * 4 + c];
            uint4 v3 = hq[(size_t)s3 * 4 + c];
            float w0 = dinv[s0], w1 = dinv[s1], w2 = dinv[s2], w3 = dinv[s3];
            i += 16;
            if (i + 16 <= end) {          // prefetch next batch's indices
                s0 = colsrc[i + g];      s1 = colsrc[i + g + 4];
                s2 = colsrc[i + g + 8];  s3 = colsrc[i + g + 12];
            }
            acc_fp8x16_fma(a, v0, w0); acc_fp8x16_fma(a, v1, w1);
            acc_fp8x16_fma(a, v2, w2); acc_fp8x16_fma(a, v3, w3);
        }
        for (; i + 4 <= end; i += 4) {    // 8-edge pad remainder (0 or 2 iters)
            int sx = colsrc[i + g];
            acc_fp8x16_fma(a, hq[(size_t)sx * 4 + c], dinv[sx]);
        }

#pragma unroll
        for (int j = 0; j < 8; j++) { // combine the 4 edge groups (bits 2-3)
            a[j].x += __shfl_xor(a[j].x, 4, 64);
            a[j].y += __shfl_xor(a[j].y, 4, 64);
            a[j].x += __shfl_xor(a[j].x, 8, 64);
            a[j].y += __shfl_xor(a[j].y, 8, 64);
        }

        if (g == 0) {                 // relu(dinv*agg + b1-half) -> LDS row
            float* rbase = &rows[wave][n][c * 16];
#pragma unroll
            for (int t = 0; t < 4; t++) {
                float4 bb = ((const float4*)b1)[p * 16 + c * 4 + t];
                float4 o;
                o.x = fmaxf(a[2 * t].x * dvd + bb.x, 0.0f);
                o.y = fmaxf(a[2 * t].y * dvd + bb.y, 0.0f);
                o.z = fmaxf(a[2 * t + 1].x * dvd + bb.z, 0.0f);
                o.w = fmaxf(a[2 * t + 1].y * dvd + bb.w, 0.0f);
                *(float4*)(rbase + 4 * t) = o;
            }
        }
    }
    __syncthreads();

    // partial gemm2: lane = node n2 (bits 4-5) x col (bits 0-3); 64-k dot.
    const int n2 = lane >> 4, col = lane & 15;
    const int d2 = (blockIdx.x >> 1) * 16 + wave * 4 + n2;
    if (d2 < N) {
        const float* r = &rows[wave][n2][0];
        float p0 = 0.0f, p1 = 0.0f;
#pragma unroll
        for (int k = 0; k < 32; k++) {       // 2-way ILP
            p0 = fmaf(r[k],      w2s[k * 16 + col],        p0);
            p1 = fmaf(r[k + 32], w2s[(k + 32) * 16 + col], p1);
        }
        atomicAdd(&h2acc[(size_t)d2 * 16 + col], p0 + p1);
    }
}

// ---------------- K3b: h2 convert  h2h[s] = fp16(h2acc[s] * dinv[s]) ---------
__global__ __launch_bounds__(256)
void h2cvt_kernel(const float* __restrict__ h2acc, const float* __restrict__ dinv,
                  unsigned* __restrict__ h2h, int N) {
    int idx = blockIdx.x * 256 + threadIdx.x;   // one float4 = quarter row
    if (idx >= (N + 1) * 4) return;
    float dv = dinv[idx >> 2];
    float4 v = ((const float4*)h2acc)[idx];
    __half2 lo = __floats2half2_rn(v.x * dv, v.y * dv);
    __half2 hi = __floats2half2_rn(v.z * dv, v.w * dv);
    ((uint2*)h2h)[idx] = make_uint2(*(unsigned*)&lo, *(unsigned*)&hi);
}

// ---------------- K4: fused layer-2 pull + log_softmax (fp16 gathers) ---------
// Lane = node n (bits 4-5) x edge-group g (bits 1-3) x 16B chunk c (bit 0).
// Batch = 8 edges/node (pad-8); 2-deep gather pipeline. Rows PRESCALED by
// dinv[s], so the loop is pure sum; final = a*dinv[d] + b2.
__global__ __launch_bounds__(256)
void l2_kernel(const int* __restrict__ rowptr, const int* __restrict__ rowcnt,
               const int* __restrict__ colsrc,
               const float* __restrict__ dinv, const unsigned* __restrict__ h2s,
               const float* __restrict__ b2, float* __restrict__ out, int N) {
    const int tid = threadIdx.x;
    const int wave = tid >> 6, lane = tid & 63;
    const int n = lane >> 4;          // node 0..3 within wave
    const int g = (lane >> 1) & 7;    // edge group 0..7
    const int c = lane & 1;           // 16B chunk (8 fp16 feats, c*8..c*8+7)
    const int d = blockIdx.x * 16 + wave * 4 + n;
    if (d >= N) return;
    const uint4* h2q = (const uint4*)h2s;   // node row = 2 uint4 (32 B)

    f32x2 a[4];
#pragma unroll
    for (int j = 0; j < 4; j++) a[j] = (f32x2)0.0f;

    if (g == 0)                        // self-loop term (prescaled by dinv[d])
        acc_fp16x8(a, h2q[(size_t)d * 2 + c]);

    int i = rowptr[d];
    const int end = i + rowcnt[d];     // multiple of 8
    uint4 v; int s2 = 0;
    if (i < end) {
        int s = colsrc[i + g];
        v = h2q[(size_t)s * 2 + c];
    }
    if (i + 8 < end) s2 = colsrc[i + 8 + g];
    while (i < end) {
        uint4 vc = v;
        if (i + 8 < end) v = h2q[(size_t)s2 * 2 + c];
        if (i + 16 < end) s2 = colsrc[i + 16 + g];
        i += 8;
        acc_fp16x8(a, vc);
    }

#pragma unroll
    for (int j = 0; j < 4; j++) {      // combine the 8 edge groups (bits 1-3)
#pragma unroll
        for (int off = 2; off <= 8; off <<= 1) {
            a[j].x += __shfl_xor(a[j].x, off, 64);
            a[j].y += __shfl_xor(a[j].y, off, 64);
        }
    }

    const float dv = dinv[d];
    const float* af = (const float*)a;     // feats c*8 .. c*8+7
    float v8[8];
#pragma unroll
    for (int j = 0; j < 8; j++) v8[j] = af[j] * dv + b2[c * 8 + j];

    float m = v8[0];
#pragma unroll
    for (int j = 1; j < 8; j++) m = fmaxf(m, v8[j]);
    m = fmaxf(m, __shfl_xor(m, 1, 64));    // combine c-halves
    float e = 0.0f;
#pragma unroll
    for (int j = 0; j < 8; j++) e += expf(v8[j] - m);
    e += __shfl_xor(e, 1, 64);
    float lse = m + logf(e);

    if (g == 0) {
        float4 o0 = make_float4(v8[0] - lse, v8[1] - lse, v8[2] - lse, v8[3] - lse);
        float4 o1 = make_float4(v8[4] - lse, v8[5] - lse, v8[6] - lse, v8[7] - lse);
        float4* op = (float4*)(out + (size_t)d * 16 + c * 8);
        op[0] = o0; op[1] = o1;
    }
}

extern "C" void kernel_launch(void* const* d_in, const int* in_sizes, int n_in,
                              void* d_out, int out_size, void* d_ws, size_t ws_size,
                              hipStream_t stream) {
    const float* x  = (const float*)d_in[0];
    const int*  ei  = (const int*)d_in[1];
    const float* W1 = (const float*)d_in[2];
    const float* b1 = (const float*)d_in[3];
    const float* W2 = (const float*)d_in[4];
    const float* b2 = (const float*)d_in[5];
    float* out = (float*)d_out;

    const int N = in_sizes[0] / 128;   // 50000 (< 65536 required for uint packing)
    const int E = in_sizes[1] / 2;     // 800000
    const int* src = ei;
    const int* dst = ei + E;
    const int nbuckets = (N + 255) >> NBUCKET_SHIFT;   // 196 (< 256 required)
    const int nbins = (E + BIN_CHUNK - 1) / BIN_CHUNK; // 196
    const int g1blocks = (N + 63) / 64;                // 782 gemm1 blocks

    // Workspace layout (4B units):
    //   dinv    : N+16 floats (dinv[N] = 0)
    //   rowptr  : N ints (padded starts)
    //   rowcnt  : N ints (padded degrees, x8)
    //   bcur    : 256 ints   \ single memset region (bcur + h2acc)
    //   h2acc   : (N+1)*16 f32/
    //   colsrc  : nbuckets*CCAP ints (5.4 MB)
    //   pairs   : nbuckets*CAP uints (4.0 MB; dead after K2 -> h2h overlays)
    //   h1b     : 2 planes x (N+1)*16 uints (6.4 MB; 64B fp8 rows; row N = 0)
    float*          wsf     = (float*)d_ws;
    float*          dinv    = wsf;
    int*            rowptr  = (int*)(wsf + N + 16);
    int*            rowcnt  = rowptr + N;
    int*            bcur    = rowcnt + N;
    float*          h2acc   = (float*)(bcur + 256);
    int*            colsrc  = (int*)(h2acc + (size_t)(N + 1) * 16);
    unsigned*       pairs   = (unsigned*)(colsrc + (size_t)nbuckets * CCAP);
    unsigned*       h1b     = pairs + (size_t)nbuckets * CAP;
    unsigned*       h2h     = pairs;   // overlays dead pairs (1.6 MB of 4.0 MB)

    // ---- K1: bin (blocks [0,nbins)) || gemm1 (blocks [nbins,nbins+g1blocks)) ----
    hipMemsetAsync(bcur, 0, (256 + (size_t)(N + 1) * 16) * sizeof(int), stream);
    bin_gemm1_kernel<<<nbins + g1blocks, 256, 0, stream>>>(src, dst, bcur, pairs,
                                                           E, nbuckets, nbins,
                                                           x, W1, h1b, N);

    // ---- K2: CSR build (rowptr/rowcnt/dinv/colsrc) ----
    bucket_build_kernel<<<nbuckets, 256, 0, stream>>>(bcur, pairs, rowptr, rowcnt,
                                                      dinv, colsrc, h1b, N, nbuckets);

    // ---- K3: plane-split layer-1 pull + partial gemm2 (f32 atomics) ----
    l1_fused_kernel<<<((N + 15) / 16) * 2, 256, 0, stream>>>(rowptr, rowcnt, colsrc,
                                                             dinv, h1b, b1, W2,
                                                             h2acc, N);

    // ---- K3b: h2h = fp16(h2acc * dinv)  (prescaled 32 B rows for l2) ----
    h2cvt_kernel<<<((N + 1) * 4 + 255) / 256, 256, 0, stream>>>(h2acc, dinv, h2h, N);

    // ---- K4: fused pull-aggregation 2 + bias + log_softmax ----
    l2_kernel<<<(N + 15) / 16, 256, 0, stream>>>(rowptr, rowcnt, colsrc, dinv, h2h,
                                                 b2, out, N);
}